// Round 4
// baseline (2928.694 us; speedup 1.0000x reference)
//
#include <hip/hip_runtime.h>
#include <cstdint>

typedef unsigned short u16;
typedef __attribute__((ext_vector_type(4))) float f32x4;
typedef __attribute__((ext_vector_type(8))) __bf16 bf16x8;
typedef __attribute__((ext_vector_type(8))) short short8;

typedef __attribute__((address_space(1))) void g_void;
typedef __attribute__((address_space(3))) void l_void;

__device__ __forceinline__ u16 f2bf(float f) {
  uint32_t u = __builtin_bit_cast(uint32_t, f);
  u += 0x7FFFu + ((u >> 16) & 1u);
  return (u16)(u >> 16);
}
__device__ __forceinline__ float bf2f(u16 h) {
  uint32_t u = ((uint32_t)h) << 16;
  return __builtin_bit_cast(float, u);
}

__device__ __forceinline__ void gload16(const void* g, void* l) {
  __builtin_amdgcn_global_load_lds((g_void*)g, (l_void*)l, 16, 0, 0);
}

// branchless GELU: erf via A&S 7.1.26 (max abs err 1.5e-7)
__device__ __forceinline__ float gelu_exact(float x) {
  float a = x * 0.70710678118654752f;
  float s = fabsf(a);
  float t = __builtin_amdgcn_rcpf(fmaf(0.3275911f, s, 1.0f));
  float p = fmaf(fmaf(fmaf(fmaf(1.061405429f, t, -1.453152027f), t, 1.421413741f), t,
                      -0.284496736f), t, 0.254829592f);
  p *= t;
  float e = __expf(-s * s);
  float er = fmaf(-p, e, 1.0f);
  er = copysignf(er, a);
  return 0.5f * x * (1.0f + er);
}

// ---------------- weight transpose + bf16 convert: Wt[n][k] = W[k][n] ----------------
__global__ void transpose_w(const float* __restrict__ W, u16* __restrict__ Wt, int K, int N) {
  __shared__ float t[32][33];
  const int nb = blockIdx.x * 32, kb = blockIdx.y * 32;
  const int tx = threadIdx.x, ty = threadIdx.y;
#pragma unroll
  for (int i = 0; i < 32; i += 8)
    t[ty + i][tx] = W[(size_t)(kb + ty + i) * N + nb + tx];
  __syncthreads();
#pragma unroll
  for (int i = 0; i < 32; i += 8)
    Wt[(size_t)(nb + ty + i) * K + kb + tx] = f2bf(t[tx][ty + i]);
}

// ---------------- embedding (bf16 residual stream) ----------------
__global__ void embed_k(const int* __restrict__ z, const int* __restrict__ hgs,
                        const float* __restrict__ ae, const float* __restrict__ ne,
                        u16* __restrict__ xb) {
  const int row = blockIdx.x;
  const int b = row >> 7, tl = row & 127;
  int ia = 1, in_ = 0;
  if (tl > 0) { ia = z[b * 127 + tl - 1] + 2; in_ = hgs[b * 127 + tl - 1] + 2; }
  const float* ar = ae + (size_t)ia * 1024;
  const float* nr = ne + (size_t)in_ * 1024;
  for (int c = threadIdx.x; c < 1024; c += 256)
    xb[(size_t)row * 1024 + c] = f2bf(ar[c] + nr[c]);
}

// ---------------- distance bin index table (np.digitize semantics) ----------------
__global__ void didx_k(const float* __restrict__ pos, unsigned char* __restrict__ didx) {
  __shared__ float edges[85];
  const int bq = blockIdx.x;
  const int b = bq >> 7, lq = bq & 127;
  const int lk = threadIdx.x;
  if (threadIdx.x < 85) {
    const int k = threadIdx.x;
    double e = 0.75 + 0.05 * (double)k;
    float ef = (float)e;
    if (k == 0) ef = -1.0f; else if (k == 1) ef = 0.0f; else if (k == 2) ef = 0.01f;
    edges[k] = ef;
  }
  __syncthreads();
  unsigned char r;
  if (lq == 0 || lk == 0) {
    r = 1;
  } else {
    const float* pi = pos + ((size_t)b * 127 + lq - 1) * 3;
    const float* pj = pos + ((size_t)b * 127 + lk - 1) * 3;
    const float dx = pi[0] - pj[0], dy = pi[1] - pj[1], dz = pi[2] - pj[2];
    const float d = sqrtf(dx * dx + dy * dy + dz * dz);
    int c = 0;
#pragma unroll
    for (int k2 = 0; k2 < 85; ++k2) c += (edges[k2] <= d) ? 1 : 0;
    r = (unsigned char)c;
  }
  didx[(size_t)b * 16384 + lq * 128 + lk] = r;
}

// ---------------- 128x128 BK=64 GEMM, 2 blocks/CU, stage-early double buffer ----------------
// MODE 0: qkv scatter -> Q(B,H,L,d) K(B,H,L,d) V(B,H,d,L)   MODE 1: plain bf16   MODE 2: gelu bf16
// LDS: 2 buf x 2 op x 2 kh x 8KB slab (slab = 128 rows x 32 cols bf16, st_16x32 swizzled) = 64KB
template <int MODE>
__launch_bounds__(256, 2)
__global__ void gemm128(const u16* __restrict__ A, const u16* __restrict__ Bt,
                        const float* __restrict__ bias,
                        u16* __restrict__ O0, u16* __restrict__ O1, u16* __restrict__ O2,
                        int N, int K) {
  extern __shared__ char lds[];
  const int tid = threadIdx.x;
  const int w = tid >> 6, l = tid & 63;
  const int wr = w >> 1, wc = w & 1;
  // bijective XCD swizzle; bm fastest within XCD (B-panel L2-resident, A streams)
  const int nwg = gridDim.x;
  const int wg = (blockIdx.x & 7) * (nwg >> 3) + (blockIdx.x >> 3);
  const int bm = wg & 63;   // M = 8192 -> 64 tiles always
  const int bn = wg >> 6;
  const int NT = K >> 6;

  // staging: rows w*16+(l>>2) and +64; inverse st_16x32 swizzle on global source col
  const int r15 = l >> 2;
  const int colc = ((((l & 3) << 4) ^ ((r15 & 8) << 2)) >> 1);  // element offset
  const int row0 = w * 16 + r15;
  const size_t abase = (size_t)(bm * 128 + row0) * K + colc;
  const size_t bbase = (size_t)(bn * 128 + row0) * K + colc;
  const int ldst = w << 10;

  auto stage = [&](int t, int buf) {
    const int kb = t << 6;
#pragma unroll
    for (int kh = 0; kh < 2; ++kh) {
      char* sa = lds + (((((buf << 1) | 0) << 1) | kh) << 13);
      char* sb = lds + (((((buf << 1) | 1) << 1) | kh) << 13);
      gload16(A + abase + kb + kh * 32, sa + ldst);
      gload16(A + abase + (size_t)64 * K + kb + kh * 32, sa + 4096 + ldst);
      gload16(Bt + bbase + kb + kh * 32, sb + ldst);
      gload16(Bt + bbase + (size_t)64 * K + kb + kh * 32, sb + 4096 + ldst);
    }
  };

  // swizzled fragment read offset within slab
  const int lo = ((l & 15) << 6) + ((((l >> 4) << 4)) ^ ((l & 8) << 2));
  auto ldA = [&](int buf, int kh, bf16x8* af) {
    const char* slab = lds + (((((buf << 1) | 0) << 1) | kh) << 13) + (wr << 12);
#pragma unroll
    for (int i = 0; i < 4; ++i) af[i] = *(const bf16x8*)(slab + (i << 10) + lo);
  };
  auto ldB = [&](int buf, int kh, bf16x8* bf) {
    const char* slab = lds + (((((buf << 1) | 1) << 1) | kh) << 13) + (wc << 12);
#pragma unroll
    for (int i = 0; i < 4; ++i) bf[i] = *(const bf16x8*)(slab + (i << 10) + lo);
  };

  f32x4 acc[4][4];
#pragma unroll
  for (int m = 0; m < 4; ++m)
#pragma unroll
    for (int n = 0; n < 4; ++n) acc[m][n] = f32x4{0.f, 0.f, 0.f, 0.f};

  stage(0, 0);
  __syncthreads();

  for (int t = 0; t < NT; ++t) {
    const int buf = t & 1;
    if (t + 1 < NT) stage(t + 1, buf ^ 1);
#pragma unroll
    for (int kh = 0; kh < 2; ++kh) {
      bf16x8 af[4], bf[4];
      ldA(buf, kh, af);
      ldB(buf, kh, bf);
      __builtin_amdgcn_s_setprio(1);
#pragma unroll
      for (int m = 0; m < 4; ++m)
#pragma unroll
        for (int n = 0; n < 4; ++n)
          acc[m][n] = __builtin_amdgcn_mfma_f32_16x16x32_bf16(af[m], bf[n], acc[m][n], 0, 0, 0);
      __builtin_amdgcn_s_setprio(0);
    }
    __syncthreads();  // drains vmcnt: next tile resident; LDS reads of buf done
  }

  // epilogue
  const int fr = l & 15, fq = l >> 4;
  const int colb = bn * 128 + wc * 64;
  const int rowb = bm * 128 + wr * 64;
  float bv[4];
#pragma unroll
  for (int n = 0; n < 4; ++n) bv[n] = bias[colb + n * 16 + fr];
  const int region = colb >> 10;

#pragma unroll
  for (int m = 0; m < 4; ++m) {
#pragma unroll
    for (int n = 0; n < 4; ++n) {
      const int col = colb + n * 16 + fr;
      if (MODE == 0 && region == 2) {
        // V: pack 4 consecutive tl into one 8B store
        const int row0_ = rowb + m * 16 + fq * 4;
        const int bI = row0_ >> 7, tl0 = row0_ & 127;
        const int c = col & 1023, h = c >> 6, d = c & 63;
        ushort4 pk;
        pk.x = f2bf(acc[m][n][0] + bv[n]);
        pk.y = f2bf(acc[m][n][1] + bv[n]);
        pk.z = f2bf(acc[m][n][2] + bv[n]);
        pk.w = f2bf(acc[m][n][3] + bv[n]);
        *(ushort4*)&O2[(((size_t)bI * 16 + h) * 64 + d) * 128 + tl0] = pk;
      } else {
#pragma unroll
        for (int j = 0; j < 4; ++j) {
          const int row = rowb + m * 16 + fq * 4 + j;
          float v = acc[m][n][j] + bv[n];
          if (MODE == 2) v = gelu_exact(v);
          if (MODE == 0) {
            const int bI = row >> 7, tl = row & 127;
            const int c = col & 1023, h = c >> 6, d = c & 63;
            if (region == 0) O0[(((size_t)bI * 16 + h) * 128 + tl) * 64 + d] = f2bf(v);
            else             O1[(((size_t)bI * 16 + h) * 128 + tl) * 64 + d] = f2bf(v);
          } else {
            O0[(size_t)row * N + col] = f2bf(v);
          }
        }
      }
    }
  }
}

// ---------------- fused attention: one block per (b,h) ----------------
__launch_bounds__(256)
__global__ void attn_kernel(const u16* __restrict__ Qg, const u16* __restrict__ Kg,
                            const u16* __restrict__ Vg,
                            const unsigned char* __restrict__ didx,
                            const float* __restrict__ demb_g,
                            u16* __restrict__ Og) {
  __shared__ u16 QK[2 * 128 * 64];
  __shared__ u16 Vt[64 * 128];
  __shared__ float dh[86];
  const int tid = threadIdx.x;
  const int wv = tid >> 6;
  const int l = tid & 63;
  const int bh = blockIdx.x;
  const int b = bh >> 4, h = bh & 15;

  for (int i = tid; i < 86; i += 256) dh[i] = demb_g[i * 16 + h];

  const char* Qs = (const char*)(Qg + (size_t)bh * 8192);
  const char* Ks = (const char*)(Kg + (size_t)bh * 8192);
  const char* Vs = (const char*)(Vg + (size_t)bh * 8192);
  char* QKb = (char*)QK;
  char* Vtb = (char*)Vt;
#pragma unroll
  for (int it = 0; it < 4; ++it) {
    const int r = it * 32 + (tid >> 3);
    const int cb = (tid & 7) * 16;
    const int sw = cb ^ ((r & 7) << 4);
    *(uint4*)(QKb + r * 128 + sw) = *(const uint4*)(Qs + r * 128 + cb);
    *(uint4*)(QKb + 16384 + r * 128 + sw) = *(const uint4*)(Ks + r * 128 + cb);
  }
#pragma unroll
  for (int it = 0; it < 4; ++it) {
    const int r = it * 16 + (tid >> 4);
    const int cb = (tid & 15) * 16;
    const int sw = cb ^ ((r & 7) << 4);
    *(uint4*)(Vtb + r * 256 + sw) = *(const uint4*)(Vs + r * 256 + cb);
  }
  __syncthreads();

  f32x4 s[2][8];
#pragma unroll
  for (int m = 0; m < 2; ++m)
#pragma unroll
    for (int n = 0; n < 8; ++n) s[m][n] = f32x4{0.f, 0.f, 0.f, 0.f};
#pragma unroll
  for (int kk = 0; kk < 2; ++kk) {
    bf16x8 qa[2], kb[8];
#pragma unroll
    for (int m = 0; m < 2; ++m) {
      const int qr = wv * 32 + m * 16 + (l & 15);
      qa[m] = *(const bf16x8*)(QKb + qr * 128 + ((kk * 64 + (l >> 4) * 16) ^ ((qr & 7) << 4)));
    }
#pragma unroll
    for (int n = 0; n < 8; ++n) {
      const int kr = n * 16 + (l & 15);
      kb[n] = *(const bf16x8*)(QKb + 16384 + kr * 128 + ((kk * 64 + (l >> 4) * 16) ^ ((kr & 7) << 4)));
    }
#pragma unroll
    for (int m = 0; m < 2; ++m)
#pragma unroll
      for (int n = 0; n < 8; ++n)
        s[m][n] = __builtin_amdgcn_mfma_f32_16x16x32_bf16(qa[m], kb[n], s[m][n], 0, 0, 0);
  }

  const unsigned char* dd = didx + (size_t)b * 16384;
  float rinv[2][4];
#pragma unroll
  for (int m = 0; m < 2; ++m) {
#pragma unroll
    for (int j = 0; j < 4; ++j) {
      const int lq = wv * 32 + m * 16 + (l >> 4) * 4 + j;
      const unsigned char* drow = dd + lq * 128;
      float vals[8];
#pragma unroll
      for (int n = 0; n < 8; ++n) {
        const int lk = n * 16 + (l & 15);
        vals[n] = s[m][n][j] * 0.125f + dh[drow[lk]];
      }
      float mx = vals[0];
#pragma unroll
      for (int n = 1; n < 8; ++n) mx = fmaxf(mx, vals[n]);
#pragma unroll
      for (int o = 1; o < 16; o <<= 1) mx = fmaxf(mx, __shfl_xor(mx, o, 64));
      float sum = 0.f;
#pragma unroll
      for (int n = 0; n < 8; ++n) { vals[n] = expf(vals[n] - mx); sum += vals[n]; }
#pragma unroll
      for (int o = 1; o < 16; o <<= 1) sum += __shfl_xor(sum, o, 64);
      rinv[m][j] = 1.f / sum;
#pragma unroll
      for (int n = 0; n < 8; ++n) s[m][n][j] = vals[n];
    }
  }
  __syncthreads();
  char* Pb = QKb + wv * 8192;
#pragma unroll
  for (int m = 0; m < 2; ++m)
#pragma unroll
    for (int n = 0; n < 8; ++n)
#pragma unroll
      for (int j = 0; j < 4; ++j) {
        const int pr = m * 16 + (l >> 4) * 4 + j;
        const int pc = (n * 16 + (l & 15)) * 2;
        *(u16*)(Pb + pr * 256 + (pc ^ ((pr & 7) << 4))) = f2bf(s[m][n][j]);
      }
  __syncthreads();

  f32x4 o_[2][4];
#pragma unroll
  for (int m = 0; m < 2; ++m)
#pragma unroll
    for (int n = 0; n < 4; ++n) o_[m][n] = f32x4{0.f, 0.f, 0.f, 0.f};
#pragma unroll
  for (int ks = 0; ks < 4; ++ks) {
    bf16x8 pa[2], vb[4];
#pragma unroll
    for (int m = 0; m < 2; ++m) {
      const int pr = m * 16 + (l & 15);
      pa[m] = *(const bf16x8*)(Pb + pr * 256 + ((ks * 64 + (l >> 4) * 16) ^ ((pr & 7) << 4)));
    }
#pragma unroll
    for (int n = 0; n < 4; ++n) {
      const int vr = n * 16 + (l & 15);
      vb[n] = *(const bf16x8*)(Vtb + vr * 256 + ((ks * 64 + (l >> 4) * 16) ^ ((vr & 7) << 4)));
    }
#pragma unroll
    for (int m = 0; m < 2; ++m)
#pragma unroll
      for (int n = 0; n < 4; ++n)
        o_[m][n] = __builtin_amdgcn_mfma_f32_16x16x32_bf16(pa[m], vb[n], o_[m][n], 0, 0, 0);
  }
#pragma unroll
  for (int m = 0; m < 2; ++m)
#pragma unroll
    for (int n = 0; n < 4; ++n)
#pragma unroll
      for (int j = 0; j < 4; ++j) {
        const int lo2 = wv * 32 + m * 16 + (l >> 4) * 4 + j;
        const int d = n * 16 + (l & 15);
        Og[((size_t)b * 128 + lo2) * 1024 + h * 64 + d] = f2bf(o_[m][n][j] * rinv[m][j]);
      }
}

// ---------------- residual + LayerNorm, bf16 stream, vectorized ----------------
__launch_bounds__(256)
__global__ void ln_res(u16* __restrict__ xb, const u16* __restrict__ o,
                       const float* __restrict__ gam, const float* __restrict__ bet,
                       float* __restrict__ cls_out) {
  const int row = blockIdx.x * 4 + (threadIdx.x >> 6);
  const int l = threadIdx.x & 63;
  const size_t base = (size_t)row * 1024 + l * 16;
  float v[16];
  float s = 0.f, sq = 0.f;
  const short8 xa = *(const short8*)(xb + base);
  const short8 xc = *(const short8*)(xb + base + 8);
  const short8 oa = *(const short8*)(o + base);
  const short8 oc = *(const short8*)(o + base + 8);
#pragma unroll
  for (int i = 0; i < 8; ++i) {
    v[i] = bf2f((u16)xa[i]) + bf2f((u16)oa[i]);
    v[i + 8] = bf2f((u16)xc[i]) + bf2f((u16)oc[i]);
  }
#pragma unroll
  for (int i = 0; i < 16; ++i) { s += v[i]; sq += v[i] * v[i]; }
#pragma unroll
  for (int off = 1; off < 64; off <<= 1) {
    s += __shfl_xor(s, off, 64);
    sq += __shfl_xor(sq, off, 64);
  }
  const float mean = s * (1.f / 1024.f);
  const float var = sq * (1.f / 1024.f) - mean * mean;
  const float rstd = rsqrtf(var + 1e-5f);
  const int c0 = l * 16;
  short8 ra, rc;
#pragma unroll
  for (int i = 0; i < 8; ++i) {
    const float ya = (v[i] - mean) * rstd * gam[c0 + i] + bet[c0 + i];
    const float yc = (v[i + 8] - mean) * rstd * gam[c0 + 8 + i] + bet[c0 + 8 + i];
    ra[i] = (short)f2bf(ya);
    rc[i] = (short)f2bf(yc);
    if ((row & 127) == 0) {
      cls_out[(size_t)(row >> 7) * 1024 + c0 + i] = ya;
      cls_out[(size_t)(row >> 7) * 1024 + c0 + 8 + i] = yc;
    }
  }
  *(short8*)(xb + base) = ra;
  *(short8*)(xb + base + 8) = rc;
}

extern "C" void kernel_launch(void* const* d_in, const int* in_sizes, int n_in,
                              void* d_out, int out_size, void* d_ws, size_t ws_size,
                              hipStream_t stream) {
  const int* z = (const int*)d_in[0];
  const int* hgs = (const int*)d_in[1];
  const float* pos = (const float*)d_in[2];
  const float* atoms_emb = (const float*)d_in[4];
  const float* neigh_emb = (const float*)d_in[5];
  const float* dist_emb = (const float*)d_in[6];
  const float* Wqkv = (const float*)d_in[7];
  const float* bqkv = (const float*)d_in[8];
  const float* Wo = (const float*)d_in[9];
  const float* bo = (const float*)d_in[10];
  const float* W1 = (const float*)d_in[11];
  const float* b1f = (const float*)d_in[12];
  const float* W2 = (const float*)d_in[13];
  const float* b2f = (const float*)d_in[14];
  const float* ln1g = (const float*)d_in[15];
  const float* ln1b = (const float*)d_in[16];
  const float* ln2g = (const float*)d_in[17];
  const float* ln2b = (const float*)d_in[18];

  size_t off = 0;
  char* wsb = (char*)d_ws;
  auto alc = [&](size_t bytes) { void* p = wsb + off; off += (bytes + 255) & ~(size_t)255; return p; };
  u16* xb = (u16*)alc(8192ull * 1024 * 2);
  u16* q = (u16*)alc(8192ull * 1024 * 2);
  u16* k = (u16*)alc(8192ull * 1024 * 2);
  u16* v = (u16*)alc(8192ull * 1024 * 2);
  u16* big = (u16*)alc(8192ull * 3072 * 2);
  u16* proj = (u16*)alc(8192ull * 1024 * 2);
  u16* wqkvt = (u16*)alc(3072ull * 1024 * 2);
  u16* wot = (u16*)alc(1024ull * 1024 * 2);
  u16* w1t = (u16*)alc(3072ull * 1024 * 2);
  u16* w2t = (u16*)alc(1024ull * 3072 * 2);
  unsigned char* didx = (unsigned char*)alc(64ull * 128 * 128);

  hipFuncSetAttribute((const void*)gemm128<0>, hipFuncAttributeMaxDynamicSharedMemorySize, 65536);
  hipFuncSetAttribute((const void*)gemm128<1>, hipFuncAttributeMaxDynamicSharedMemorySize, 65536);
  hipFuncSetAttribute((const void*)gemm128<2>, hipFuncAttributeMaxDynamicSharedMemorySize, 65536);

  transpose_w<<<dim3(96, 32), dim3(32, 8), 0, stream>>>(Wqkv, wqkvt, 1024, 3072);
  transpose_w<<<dim3(32, 32), dim3(32, 8), 0, stream>>>(Wo, wot, 1024, 1024);
  transpose_w<<<dim3(96, 32), dim3(32, 8), 0, stream>>>(W1, w1t, 1024, 3072);
  transpose_w<<<dim3(32, 96), dim3(32, 8), 0, stream>>>(W2, w2t, 3072, 1024);
  embed_k<<<8192, 256, 0, stream>>>(z, hgs, atoms_emb, neigh_emb, xb);
  didx_k<<<8192, 128, 0, stream>>>(pos, didx);

  float* cls = (float*)d_out;
  for (int layer = 0; layer < 8; ++layer) {
    gemm128<0><<<1536, 256, 65536, stream>>>(xb, wqkvt, bqkv, q, k, v, 3072, 1024);
    attn_kernel<<<1024, 256, 0, stream>>>(q, k, v, didx, dist_emb, big);
    gemm128<1><<<512, 256, 65536, stream>>>(big, wot, bo, proj, nullptr, nullptr, 1024, 1024);
    ln_res<<<2048, 256, 0, stream>>>(xb, proj, ln1g, ln1b, cls);
    gemm128<2><<<1536, 256, 65536, stream>>>(xb, w1t, b1f, big, nullptr, nullptr, 3072, 1024);
    gemm128<1><<<512, 256, 65536, stream>>>(big, w2t, b2f, proj, nullptr, nullptr, 1024, 3072);
    ln_res<<<2048, 256, 0, stream>>>(xb, proj, ln2g, ln2b, cls);
  }
}

// Round 5
// 2829.335 us; speedup vs baseline: 1.0351x; 1.0351x over previous
//
#include <hip/hip_runtime.h>
#include <cstdint>
#include <math.h>

typedef unsigned short u16;
typedef __attribute__((ext_vector_type(4))) float f32x4;
typedef __attribute__((ext_vector_type(8))) __bf16 bf16x8;
typedef __attribute__((ext_vector_type(8))) short short8;

typedef __attribute__((address_space(1))) void g_void;
typedef __attribute__((address_space(3))) void l_void;

__device__ __forceinline__ u16 f2bf(float f) {
  uint32_t u = __builtin_bit_cast(uint32_t, f);
  u += 0x7FFFu + ((u >> 16) & 1u);
  return (u16)(u >> 16);
}
__device__ __forceinline__ float bf2f(u16 h) {
  uint32_t u = ((uint32_t)h) << 16;
  return __builtin_bit_cast(float, u);
}

__device__ __forceinline__ void gload16(const void* g, void* l) {
  __builtin_amdgcn_global_load_lds((g_void*)g, (l_void*)l, 16, 0, 0);
}

// branchless GELU: erf via A&S 7.1.26 (max abs err 1.5e-7)
__device__ __forceinline__ float gelu_exact(float x) {
  float a = x * 0.70710678118654752f;
  float s = fabsf(a);
  float t = __builtin_amdgcn_rcpf(fmaf(0.3275911f, s, 1.0f));
  float p = fmaf(fmaf(fmaf(fmaf(1.061405429f, t, -1.453152027f), t, 1.421413741f), t,
                      -0.284496736f), t, 0.254829592f);
  p *= t;
  float e = __expf(-s * s);
  float er = fmaf(-p, e, 1.0f);
  er = copysignf(er, a);
  return 0.5f * x * (1.0f + er);
}

// ---------------- weight transpose + bf16 convert: Wt[n][k] = W[k][n] ----------------
__global__ void transpose_w(const float* __restrict__ W, u16* __restrict__ Wt, int K, int N) {
  __shared__ float t[32][33];
  const int nb = blockIdx.x * 32, kb = blockIdx.y * 32;
  const int tx = threadIdx.x, ty = threadIdx.y;
#pragma unroll
  for (int i = 0; i < 32; i += 8)
    t[ty + i][tx] = W[(size_t)(kb + ty + i) * N + nb + tx];
  __syncthreads();
#pragma unroll
  for (int i = 0; i < 32; i += 8)
    Wt[(size_t)(nb + ty + i) * K + kb + tx] = f2bf(t[tx][ty + i]);
}

// ---------------- embedding (bf16 residual stream) ----------------
__global__ void embed_k(const int* __restrict__ z, const int* __restrict__ hgs,
                        const float* __restrict__ ae, const float* __restrict__ ne,
                        u16* __restrict__ xb) {
  const int row = blockIdx.x;
  const int b = row >> 7, tl = row & 127;
  int ia = 1, in_ = 0;
  if (tl > 0) { ia = z[b * 127 + tl - 1] + 2; in_ = hgs[b * 127 + tl - 1] + 2; }
  const float* ar = ae + (size_t)ia * 1024;
  const float* nr = ne + (size_t)in_ * 1024;
  for (int c = threadIdx.x; c < 1024; c += 256)
    xb[(size_t)row * 1024 + c] = f2bf(ar[c] + nr[c]);
}

// ---------------- attention bias mask precompute: (B,H,128,128) bf16 ----------------
// np.digitize semantics; dist_emb row 0 forced -inf
__global__ void mask_k(const float* __restrict__ pos, const float* __restrict__ demb,
                       u16* __restrict__ mask) {
  __shared__ float edges[85];
  __shared__ float dh[86 * 16];
  const int bq = blockIdx.x;
  const int b = bq >> 7, lq = bq & 127;
  const int lk = threadIdx.x;  // 128 threads
  if (lk < 85) {
    double e = 0.75 + 0.05 * (double)lk;
    float ef = (float)e;
    if (lk == 0) ef = -1.0f; else if (lk == 1) ef = 0.0f; else if (lk == 2) ef = 0.01f;
    edges[lk] = ef;
  }
  for (int i = lk; i < 86 * 16; i += 128) {
    float v = demb[i];
    if (i < 16) v = -INFINITY;
    dh[i] = v;
  }
  __syncthreads();
  int c;
  if (lq == 0 || lk == 0) {
    c = 1;
  } else {
    const float* pi = pos + ((size_t)b * 127 + lq - 1) * 3;
    const float* pj = pos + ((size_t)b * 127 + lk - 1) * 3;
    const float dx = pi[0] - pj[0], dy = pi[1] - pj[1], dz = pi[2] - pj[2];
    const float d = sqrtf(dx * dx + dy * dy + dz * dz);
    int cnt = 0;
#pragma unroll
    for (int k2 = 0; k2 < 85; ++k2) cnt += (edges[k2] <= d) ? 1 : 0;
    c = cnt;
  }
#pragma unroll
  for (int h = 0; h < 16; ++h)
    mask[(((size_t)b * 16 + h) * 128 + lq) * 128 + lk] = f2bf(dh[c * 16 + h]);
}

// ---------------- GEMM: BM=256 BN=128 BK=32, 4 waves (wave-tile 128x64), dbuf ----------------
// MODE 0: qkv scatter -> Q(B,H,L,d) K(B,H,L,d) V(B,H,d,L)   MODE 1: plain bf16   MODE 2: gelu bf16
// LDS per buf: A 256x32 (16KB, st-swizzled) + B 128x32 (8KB) = 24KB; x2 = 48KB -> 2 blocks/CU
template <int MODE>
__launch_bounds__(256, 2)
__global__ void gemmW(const u16* __restrict__ A, const u16* __restrict__ Bt,
                      const float* __restrict__ bias,
                      u16* __restrict__ O0, u16* __restrict__ O1, u16* __restrict__ O2,
                      int N, int K) {
  extern __shared__ char lds[];
  const int tid = threadIdx.x;
  const int w = tid >> 6, l = tid & 63;
  const int wr = w >> 1, wc = w & 1;
  // bijective XCD swizzle, bn fastest within XCD (A-tile reuse in L2)
  const int nwg = gridDim.x;
  const int wg = (blockIdx.x & 7) * (nwg >> 3) + (blockIdx.x >> 3);
  const int ntn = N >> 7;
  const int bm = wg / ntn, bn = wg % ntn;
  const int NT = K >> 5;

  // staging: per gload call, wave w covers rows base+w*16+(l>>2); chunk (l&3)*16B with
  // inverse st-swizzle on the global source column
  const int r15 = l >> 2;
  const int colc = ((((l & 3) << 4) ^ ((r15 & 8) << 2)) >> 1);  // element offset
  const u16* Ag = A + (size_t)(bm * 256 + w * 16 + r15) * K + colc;
  const u16* Bg = Bt + (size_t)(bn * 128 + w * 16 + r15) * K + colc;
  const int ldst = w << 10;

  auto stage = [&](int t, int buf) {
    const int kb = t << 5;
    char* base = lds + buf * 24576;
#pragma unroll
    for (int c = 0; c < 4; ++c)
      gload16(Ag + (size_t)(c * 64) * K + kb, base + c * 4096 + ldst);
#pragma unroll
    for (int c = 0; c < 2; ++c)
      gload16(Bg + (size_t)(c * 64) * K + kb, base + 16384 + c * 4096 + ldst);
  };

  // swizzled fragment read offset within a 1KB subtile (16 rows x 64B)
  const int lo = ((l & 15) << 6) + (((l >> 4) << 4) ^ ((l & 8) << 2));

  f32x4 acc[8][4];
#pragma unroll
  for (int m = 0; m < 8; ++m)
#pragma unroll
    for (int n = 0; n < 4; ++n) acc[m][n] = f32x4{0.f, 0.f, 0.f, 0.f};

  stage(0, 0);
  __syncthreads();

  for (int t = 0; t < NT; ++t) {
    const int buf = t & 1;
    if (t + 1 < NT) stage(t + 1, buf ^ 1);
    bf16x8 af[8], bf[4];
    const char* ab = lds + buf * 24576 + (wr << 13);
    const char* bb = lds + buf * 24576 + 16384 + (wc << 12);
#pragma unroll
    for (int m = 0; m < 8; ++m) af[m] = *(const bf16x8*)(ab + (m << 10) + lo);
#pragma unroll
    for (int n = 0; n < 4; ++n) bf[n] = *(const bf16x8*)(bb + (n << 10) + lo);
    __builtin_amdgcn_s_setprio(1);
#pragma unroll
    for (int m = 0; m < 8; ++m)
#pragma unroll
      for (int n = 0; n < 4; ++n)
        acc[m][n] = __builtin_amdgcn_mfma_f32_16x16x32_bf16(af[m], bf[n], acc[m][n], 0, 0, 0);
    __builtin_amdgcn_s_setprio(0);
    __syncthreads();  // drains vmcnt: stage(t+1) resident; ds_reads of buf complete
  }

  // epilogue
  const int fr = l & 15, fq = l >> 4;
  const int colb = bn * 128 + wc * 64;
  const int rowb = bm * 256 + wr * 128;
  float bv[4];
#pragma unroll
  for (int n = 0; n < 4; ++n) bv[n] = bias[colb + n * 16 + fr];
  const int region = colb >> 10;

#pragma unroll
  for (int m = 0; m < 8; ++m) {
#pragma unroll
    for (int n = 0; n < 4; ++n) {
      const int col = colb + n * 16 + fr;
      if (MODE == 0 && region == 2) {
        const int row0_ = rowb + m * 16 + fq * 4;
        const int bI = row0_ >> 7, tl0 = row0_ & 127;
        const int c = col & 1023, h = c >> 6, d = c & 63;
        ushort4 pk;
        pk.x = f2bf(acc[m][n][0] + bv[n]);
        pk.y = f2bf(acc[m][n][1] + bv[n]);
        pk.z = f2bf(acc[m][n][2] + bv[n]);
        pk.w = f2bf(acc[m][n][3] + bv[n]);
        *(ushort4*)&O2[(((size_t)bI * 16 + h) * 64 + d) * 128 + tl0] = pk;
      } else {
#pragma unroll
        for (int j = 0; j < 4; ++j) {
          const int row = rowb + m * 16 + fq * 4 + j;
          float v = acc[m][n][j] + bv[n];
          if (MODE == 2) v = gelu_exact(v);
          if (MODE == 0) {
            const int bI = row >> 7, tl = row & 127;
            const int c = col & 1023, h = c >> 6, d = c & 63;
            if (region == 0) O0[(((size_t)bI * 16 + h) * 128 + tl) * 64 + d] = f2bf(v);
            else             O1[(((size_t)bI * 16 + h) * 128 + tl) * 64 + d] = f2bf(v);
          } else {
            O0[(size_t)row * N + col] = f2bf(v);
          }
        }
      }
    }
  }
}

// ---------------- fused attention: one block per (b,h), precomputed bf16 mask ----------------
__launch_bounds__(256)
__global__ void attn_kernel(const u16* __restrict__ Qg, const u16* __restrict__ Kg,
                            const u16* __restrict__ Vg,
                            const u16* __restrict__ mask,
                            u16* __restrict__ Og) {
  __shared__ u16 QK[2 * 128 * 64];
  __shared__ u16 Vt[64 * 128];
  const int tid = threadIdx.x;
  const int wv = tid >> 6;
  const int l = tid & 63;
  const int bh = blockIdx.x;
  const int b = bh >> 4;

  const char* Qs = (const char*)(Qg + (size_t)bh * 8192);
  const char* Ks = (const char*)(Kg + (size_t)bh * 8192);
  const char* Vs = (const char*)(Vg + (size_t)bh * 8192);
  char* QKb = (char*)QK;
  char* Vtb = (char*)Vt;
#pragma unroll
  for (int it = 0; it < 4; ++it) {
    const int r = it * 32 + (tid >> 3);
    const int cb = (tid & 7) * 16;
    const int sw = cb ^ ((r & 7) << 4);
    *(uint4*)(QKb + r * 128 + sw) = *(const uint4*)(Qs + r * 128 + cb);
    *(uint4*)(QKb + 16384 + r * 128 + sw) = *(const uint4*)(Ks + r * 128 + cb);
  }
#pragma unroll
  for (int it = 0; it < 4; ++it) {
    const int r = it * 16 + (tid >> 4);
    const int cb = (tid & 15) * 16;
    const int sw = cb ^ ((r & 7) << 4);
    *(uint4*)(Vtb + r * 256 + sw) = *(const uint4*)(Vs + r * 256 + cb);
  }
  __syncthreads();

  f32x4 s[2][8];
#pragma unroll
  for (int m = 0; m < 2; ++m)
#pragma unroll
    for (int n = 0; n < 8; ++n) s[m][n] = f32x4{0.f, 0.f, 0.f, 0.f};
#pragma unroll
  for (int kk = 0; kk < 2; ++kk) {
    bf16x8 qa[2], kb[8];
#pragma unroll
    for (int m = 0; m < 2; ++m) {
      const int qr = wv * 32 + m * 16 + (l & 15);
      qa[m] = *(const bf16x8*)(QKb + qr * 128 + ((kk * 64 + (l >> 4) * 16) ^ ((qr & 7) << 4)));
    }
#pragma unroll
    for (int n = 0; n < 8; ++n) {
      const int kr = n * 16 + (l & 15);
      kb[n] = *(const bf16x8*)(QKb + 16384 + kr * 128 + ((kk * 64 + (l >> 4) * 16) ^ ((kr & 7) << 4)));
    }
#pragma unroll
    for (int m = 0; m < 2; ++m)
#pragma unroll
      for (int n = 0; n < 8; ++n)
        s[m][n] = __builtin_amdgcn_mfma_f32_16x16x32_bf16(qa[m], kb[n], s[m][n], 0, 0, 0);
  }

  const u16* mbase = mask + (size_t)bh * 16384;
  float rinv[2][4];
#pragma unroll
  for (int m = 0; m < 2; ++m) {
#pragma unroll
    for (int j = 0; j < 4; ++j) {
      const int lq = wv * 32 + m * 16 + (l >> 4) * 4 + j;
      const u16* mrow = mbase + lq * 128 + (l & 15);
      float vals[8];
#pragma unroll
      for (int n = 0; n < 8; ++n)
        vals[n] = fmaf(s[m][n][j], 0.125f, bf2f(mrow[n * 16]));
      float mx = vals[0];
#pragma unroll
      for (int n = 1; n < 8; ++n) mx = fmaxf(mx, vals[n]);
#pragma unroll
      for (int o = 1; o < 16; o <<= 1) mx = fmaxf(mx, __shfl_xor(mx, o, 64));
      float sum = 0.f;
#pragma unroll
      for (int n = 0; n < 8; ++n) { vals[n] = expf(vals[n] - mx); sum += vals[n]; }
#pragma unroll
      for (int o = 1; o < 16; o <<= 1) sum += __shfl_xor(sum, o, 64);
      rinv[m][j] = 1.f / sum;
#pragma unroll
      for (int n = 0; n < 8; ++n) s[m][n][j] = vals[n];
    }
  }
  __syncthreads();
  char* Pb = QKb + wv * 8192;
#pragma unroll
  for (int m = 0; m < 2; ++m)
#pragma unroll
    for (int n = 0; n < 8; ++n)
#pragma unroll
      for (int j = 0; j < 4; ++j) {
        const int pr = m * 16 + (l >> 4) * 4 + j;
        const int pc = (n * 16 + (l & 15)) * 2;
        *(u16*)(Pb + pr * 256 + (pc ^ ((pr & 7) << 4))) = f2bf(s[m][n][j]);
      }
  __syncthreads();

  f32x4 o_[2][4];
#pragma unroll
  for (int m = 0; m < 2; ++m)
#pragma unroll
    for (int n = 0; n < 4; ++n) o_[m][n] = f32x4{0.f, 0.f, 0.f, 0.f};
#pragma unroll
  for (int ks = 0; ks < 4; ++ks) {
    bf16x8 pa[2], vb[4];
#pragma unroll
    for (int m = 0; m < 2; ++m) {
      const int pr = m * 16 + (l & 15);
      pa[m] = *(const bf16x8*)(Pb + pr * 256 + ((ks * 64 + (l >> 4) * 16) ^ ((pr & 7) << 4)));
    }
#pragma unroll
    for (int n = 0; n < 4; ++n) {
      const int vr = n * 16 + (l & 15);
      vb[n] = *(const bf16x8*)(Vtb + vr * 256 + ((ks * 64 + (l >> 4) * 16) ^ ((vr & 7) << 4)));
    }
#pragma unroll
    for (int m = 0; m < 2; ++m)
#pragma unroll
      for (int n = 0; n < 4; ++n)
        o_[m][n] = __builtin_amdgcn_mfma_f32_16x16x32_bf16(pa[m], vb[n], o_[m][n], 0, 0, 0);
  }
  const int h = bh & 15;
#pragma unroll
  for (int m = 0; m < 2; ++m)
#pragma unroll
    for (int n = 0; n < 4; ++n)
#pragma unroll
      for (int j = 0; j < 4; ++j) {
        const int lo2 = wv * 32 + m * 16 + (l >> 4) * 4 + j;
        const int d = n * 16 + (l & 15);
        Og[((size_t)b * 128 + lo2) * 1024 + h * 64 + d] = f2bf(o_[m][n][j] * rinv[m][j]);
      }
}

// ---------------- residual + LayerNorm, bf16 stream, vectorized ----------------
__launch_bounds__(256)
__global__ void ln_res(u16* __restrict__ xb, const u16* __restrict__ o,
                       const float* __restrict__ gam, const float* __restrict__ bet,
                       float* __restrict__ cls_out) {
  const int row = blockIdx.x * 4 + (threadIdx.x >> 6);
  const int l = threadIdx.x & 63;
  const size_t base = (size_t)row * 1024 + l * 16;
  float v[16];
  float s = 0.f, sq = 0.f;
  const short8 xa = *(const short8*)(xb + base);
  const short8 xc = *(const short8*)(xb + base + 8);
  const short8 oa = *(const short8*)(o + base);
  const short8 oc = *(const short8*)(o + base + 8);
#pragma unroll
  for (int i = 0; i < 8; ++i) {
    v[i] = bf2f((u16)xa[i]) + bf2f((u16)oa[i]);
    v[i + 8] = bf2f((u16)xc[i]) + bf2f((u16)oc[i]);
  }
#pragma unroll
  for (int i = 0; i < 16; ++i) { s += v[i]; sq += v[i] * v[i]; }
#pragma unroll
  for (int off = 1; off < 64; off <<= 1) {
    s += __shfl_xor(s, off, 64);
    sq += __shfl_xor(sq, off, 64);
  }
  const float mean = s * (1.f / 1024.f);
  const float var = sq * (1.f / 1024.f) - mean * mean;
  const float rstd = rsqrtf(var + 1e-5f);
  const int c0 = l * 16;
  short8 ra, rc;
#pragma unroll
  for (int i = 0; i < 8; ++i) {
    const float ya = (v[i] - mean) * rstd * gam[c0 + i] + bet[c0 + i];
    const float yc = (v[i + 8] - mean) * rstd * gam[c0 + 8 + i] + bet[c0 + 8 + i];
    ra[i] = (short)f2bf(ya);
    rc[i] = (short)f2bf(yc);
    if ((row & 127) == 0) {
      cls_out[(size_t)(row >> 7) * 1024 + c0 + i] = ya;
      cls_out[(size_t)(row >> 7) * 1024 + c0 + 8 + i] = yc;
    }
  }
  *(short8*)(xb + base) = ra;
  *(short8*)(xb + base + 8) = rc;
}

extern "C" void kernel_launch(void* const* d_in, const int* in_sizes, int n_in,
                              void* d_out, int out_size, void* d_ws, size_t ws_size,
                              hipStream_t stream) {
  const int* z = (const int*)d_in[0];
  const int* hgs = (const int*)d_in[1];
  const float* pos = (const float*)d_in[2];
  const float* atoms_emb = (const float*)d_in[4];
  const float* neigh_emb = (const float*)d_in[5];
  const float* dist_emb = (const float*)d_in[6];
  const float* Wqkv = (const float*)d_in[7];
  const float* bqkv = (const float*)d_in[8];
  const float* Wo = (const float*)d_in[9];
  const float* bo = (const float*)d_in[10];
  const float* W1 = (const float*)d_in[11];
  const float* b1f = (const float*)d_in[12];
  const float* W2 = (const float*)d_in[13];
  const float* b2f = (const float*)d_in[14];
  const float* ln1g = (const float*)d_in[15];
  const float* ln1b = (const float*)d_in[16];
  const float* ln2g = (const float*)d_in[17];
  const float* ln2b = (const float*)d_in[18];

  size_t off = 0;
  char* wsb = (char*)d_ws;
  auto alc = [&](size_t bytes) { void* p = wsb + off; off += (bytes + 255) & ~(size_t)255; return p; };
  u16* xb = (u16*)alc(8192ull * 1024 * 2);
  u16* q = (u16*)alc(8192ull * 1024 * 2);
  u16* k = (u16*)alc(8192ull * 1024 * 2);
  u16* v = (u16*)alc(8192ull * 1024 * 2);
  u16* big = (u16*)alc(8192ull * 3072 * 2);
  u16* proj = (u16*)alc(8192ull * 1024 * 2);
  u16* wqkvt = (u16*)alc(3072ull * 1024 * 2);
  u16* wot = (u16*)alc(1024ull * 1024 * 2);
  u16* w1t = (u16*)alc(3072ull * 1024 * 2);
  u16* w2t = (u16*)alc(1024ull * 3072 * 2);
  u16* mask = (u16*)alc(64ull * 16 * 128 * 128 * 2);

  hipFuncSetAttribute((const void*)gemmW<0>, hipFuncAttributeMaxDynamicSharedMemorySize, 49152);
  hipFuncSetAttribute((const void*)gemmW<1>, hipFuncAttributeMaxDynamicSharedMemorySize, 49152);
  hipFuncSetAttribute((const void*)gemmW<2>, hipFuncAttributeMaxDynamicSharedMemorySize, 49152);

  transpose_w<<<dim3(96, 32), dim3(32, 8), 0, stream>>>(Wqkv, wqkvt, 1024, 3072);
  transpose_w<<<dim3(32, 32), dim3(32, 8), 0, stream>>>(Wo, wot, 1024, 1024);
  transpose_w<<<dim3(96, 32), dim3(32, 8), 0, stream>>>(W1, w1t, 1024, 3072);
  transpose_w<<<dim3(32, 96), dim3(32, 8), 0, stream>>>(W2, w2t, 3072, 1024);
  embed_k<<<8192, 256, 0, stream>>>(z, hgs, atoms_emb, neigh_emb, xb);
  mask_k<<<8192, 128, 0, stream>>>(pos, dist_emb, mask);

  float* cls = (float*)d_out;
  for (int layer = 0; layer < 8; ++layer) {
    gemmW<0><<<768, 256, 49152, stream>>>(xb, wqkvt, bqkv, q, k, v, 3072, 1024);
    attn_kernel<<<1024, 256, 0, stream>>>(q, k, v, mask, big);
    gemmW<1><<<256, 256, 49152, stream>>>(big, wot, bo, proj, nullptr, nullptr, 1024, 1024);
    ln_res<<<2048, 256, 0, stream>>>(xb, proj, ln1g, ln1b, cls);
    gemmW<2><<<768, 256, 49152, stream>>>(xb, w1t, b1f, big, nullptr, nullptr, 3072, 1024);
    gemmW<1><<<256, 256, 49152, stream>>>(big, w2t, b2f, proj, nullptr, nullptr, 1024, 3072);
    ln_res<<<2048, 256, 0, stream>>>(xb, proj, ln2g, ln2b, cls);
  }
}

// Round 6
// 2381.859 us; speedup vs baseline: 1.2296x; 1.1879x over previous
//
#include <hip/hip_runtime.h>
#include <cstdint>
#include <math.h>

typedef unsigned short u16;
typedef __attribute__((ext_vector_type(4))) float f32x4;
typedef __attribute__((ext_vector_type(8))) __bf16 bf16x8;
typedef __attribute__((ext_vector_type(8))) short short8;

typedef __attribute__((address_space(1))) void g_void;
typedef __attribute__((address_space(3))) void l_void;

__device__ __forceinline__ u16 f2bf(float f) {
  uint32_t u = __builtin_bit_cast(uint32_t, f);
  u += 0x7FFFu + ((u >> 16) & 1u);
  return (u16)(u >> 16);
}
__device__ __forceinline__ float bf2f(u16 h) {
  uint32_t u = ((uint32_t)h) << 16;
  return __builtin_bit_cast(float, u);
}

__device__ __forceinline__ void gload16(const void* g, void* l) {
  __builtin_amdgcn_global_load_lds((g_void*)g, (l_void*)l, 16, 0, 0);
}

// branchless GELU: erf via A&S 7.1.26 (max abs err 1.5e-7)
__device__ __forceinline__ float gelu_exact(float x) {
  float a = x * 0.70710678118654752f;
  float s = fabsf(a);
  float t = __builtin_amdgcn_rcpf(fmaf(0.3275911f, s, 1.0f));
  float p = fmaf(fmaf(fmaf(fmaf(1.061405429f, t, -1.453152027f), t, 1.421413741f), t,
                      -0.284496736f), t, 0.254829592f);
  p *= t;
  float e = __expf(-s * s);
  float er = fmaf(-p, e, 1.0f);
  er = copysignf(er, a);
  return 0.5f * x * (1.0f + er);
}

// ---------------- weight transpose + bf16 convert: Wt[n][k] = W[k][n] ----------------
__global__ void transpose_w(const float* __restrict__ W, u16* __restrict__ Wt, int K, int N) {
  __shared__ float t[32][33];
  const int nb = blockIdx.x * 32, kb = blockIdx.y * 32;
  const int tx = threadIdx.x, ty = threadIdx.y;
#pragma unroll
  for (int i = 0; i < 32; i += 8)
    t[ty + i][tx] = W[(size_t)(kb + ty + i) * N + nb + tx];
  __syncthreads();
#pragma unroll
  for (int i = 0; i < 32; i += 8)
    Wt[(size_t)(nb + ty + i) * K + kb + tx] = f2bf(t[tx][ty + i]);
}

// ---------------- embedding (bf16 residual stream) ----------------
__global__ void embed_k(const int* __restrict__ z, const int* __restrict__ hgs,
                        const float* __restrict__ ae, const float* __restrict__ ne,
                        u16* __restrict__ xb) {
  const int row = blockIdx.x;
  const int b = row >> 7, tl = row & 127;
  int ia = 1, in_ = 0;
  if (tl > 0) { ia = z[b * 127 + tl - 1] + 2; in_ = hgs[b * 127 + tl - 1] + 2; }
  const float* ar = ae + (size_t)ia * 1024;
  const float* nr = ne + (size_t)in_ * 1024;
  for (int c = threadIdx.x; c < 1024; c += 256)
    xb[(size_t)row * 1024 + c] = f2bf(ar[c] + nr[c]);
}

// ---------------- attention bias mask precompute: (B,H,128,128) bf16 ----------------
__global__ void mask_k(const float* __restrict__ pos, const float* __restrict__ demb,
                       u16* __restrict__ mask) {
  __shared__ float edges[85];
  __shared__ float dh[86 * 16];
  const int bq = blockIdx.x;
  const int b = bq >> 7, lq = bq & 127;
  const int lk = threadIdx.x;  // 128 threads
  if (lk < 85) {
    double e = 0.75 + 0.05 * (double)lk;
    float ef = (float)e;
    if (lk == 0) ef = -1.0f; else if (lk == 1) ef = 0.0f; else if (lk == 2) ef = 0.01f;
    edges[lk] = ef;
  }
  for (int i = lk; i < 86 * 16; i += 128) {
    float v = demb[i];
    if (i < 16) v = -INFINITY;
    dh[i] = v;
  }
  __syncthreads();
  int c;
  if (lq == 0 || lk == 0) {
    c = 1;
  } else {
    const float* pi = pos + ((size_t)b * 127 + lq - 1) * 3;
    const float* pj = pos + ((size_t)b * 127 + lk - 1) * 3;
    const float dx = pi[0] - pj[0], dy = pi[1] - pj[1], dz = pi[2] - pj[2];
    const float d = sqrtf(dx * dx + dy * dy + dz * dz);
    int cnt = 0;
#pragma unroll
    for (int k2 = 0; k2 < 85; ++k2) cnt += (edges[k2] <= d) ? 1 : 0;
    c = cnt;
  }
#pragma unroll
  for (int h = 0; h < 16; ++h)
    mask[(((size_t)b * 16 + h) * 128 + lq) * 128 + lk] = f2bf(dh[c * 16 + h]);
}

// ---------------- pipelined GEMM: BM=128*RT, BN=128, BK=32, 4 waves, 3-buf counted vmcnt ----
// MODE 0: qkv scatter -> Q(B,H,L,d) K(B,H,L,d) V(B,H,d,L)   MODE 1: plain bf16   MODE 2: gelu
// LDS: 3 x (A BMx32 + B 128x32) st-swizzled. Depth-2 prefetch, vmcnt(loads/stage) per iter.
template <int MODE, int RT>
__launch_bounds__(256, 2)
__global__ void gemmP(const u16* __restrict__ A, const u16* __restrict__ Bt,
                      const float* __restrict__ bias,
                      u16* __restrict__ O0, u16* __restrict__ O1, u16* __restrict__ O2,
                      int N, int K) {
  extern __shared__ char lds[];
  constexpr int BM = 128 * RT;
  constexpr int ASZ = 8192 * RT;       // A slab bytes
  constexpr int SLAB = ASZ + 8192;     // + B slab
  const int tid = threadIdx.x;
  const int w = tid >> 6, l = tid & 63;
  const int wr = w >> 1, wc = w & 1;
  // bijective XCD swizzle, bn fastest within XCD (A-tile reuse in L2)
  const int nwg = gridDim.x;
  const int wg = (blockIdx.x & 7) * (nwg >> 3) + (blockIdx.x >> 3);
  const int ntn = N >> 7;
  const int bm = wg / ntn, bn = wg % ntn;
  const int NT = K >> 5;

  // staging: wave w covers rows c*64 + w*16 + (l>>2), chunk (l&3)*16B, inverse st-swizzle
  const int r15 = l >> 2;
  const int colc = ((((l & 3) << 4) ^ ((r15 & 8) << 2)) >> 1);
  const u16* Ag = A + (size_t)(bm * BM + w * 16 + r15) * K + colc;
  const u16* Bg = Bt + (size_t)(bn * 128 + w * 16 + r15) * K + colc;
  const int ldst = w << 10;

  auto stage = [&](int t, char* buf) {
    const int kb = t << 5;
#pragma unroll
    for (int c = 0; c < 2 * RT; ++c)
      gload16(Ag + (size_t)(c * 64) * K + kb, buf + c * 4096 + ldst);
#pragma unroll
    for (int c = 0; c < 2; ++c)
      gload16(Bg + (size_t)(c * 64) * K + kb, buf + ASZ + c * 4096 + ldst);
  };

  // swizzled fragment read offset within a 1KB subtile (16 rows x 64B)
  const int lo = ((l & 15) << 6) + (((l >> 4) << 4) ^ ((l & 8) << 2));

  f32x4 acc[4 * RT][4];
#pragma unroll
  for (int m = 0; m < 4 * RT; ++m)
#pragma unroll
    for (int n = 0; n < 4; ++n) acc[m][n] = f32x4{0.f, 0.f, 0.f, 0.f};

  char* p0 = lds;
  char* p1 = lds + SLAB;
  char* p2 = lds + 2 * SLAB;

  stage(0, p0);
  stage(1, p1);
  if constexpr (RT == 2) asm volatile("s_waitcnt vmcnt(6)" ::: "memory");
  else                   asm volatile("s_waitcnt vmcnt(4)" ::: "memory");
  __builtin_amdgcn_s_barrier();

  for (int t = 0; t < NT; ++t) {
    if (t + 2 < NT) stage(t + 2, p2);
    const char* ab = p0 + wr * (RT * 4096);
    const char* bb = p0 + ASZ + (wc << 12);
    bf16x8 af[4 * RT], bf[4];
#pragma unroll
    for (int m = 0; m < 4 * RT; ++m) af[m] = *(const bf16x8*)(ab + (m << 10) + lo);
#pragma unroll
    for (int n = 0; n < 4; ++n) bf[n] = *(const bf16x8*)(bb + (n << 10) + lo);
    __builtin_amdgcn_s_setprio(1);
#pragma unroll
    for (int m = 0; m < 4 * RT; ++m)
#pragma unroll
      for (int n = 0; n < 4; ++n)
        acc[m][n] = __builtin_amdgcn_mfma_f32_16x16x32_bf16(af[m], bf[n], acc[m][n], 0, 0, 0);
    __builtin_amdgcn_s_setprio(0);
    if (t + 2 < NT) {
      if constexpr (RT == 2) asm volatile("s_waitcnt vmcnt(6)" ::: "memory");
      else                   asm volatile("s_waitcnt vmcnt(4)" ::: "memory");
    } else {
      asm volatile("s_waitcnt vmcnt(0)" ::: "memory");
    }
    __builtin_amdgcn_s_barrier();
    char* tmp = p0; p0 = p1; p1 = p2; p2 = tmp;
  }

  // epilogue
  const int fr = l & 15, fq = l >> 4;
  const int colb = bn * 128 + wc * 64;
  const int rowb = bm * BM + wr * (64 * RT);
  float bv[4];
#pragma unroll
  for (int n = 0; n < 4; ++n) bv[n] = bias[colb + n * 16 + fr];
  const int region = colb >> 10;

#pragma unroll
  for (int m = 0; m < 4 * RT; ++m) {
#pragma unroll
    for (int n = 0; n < 4; ++n) {
      const int col = colb + n * 16 + fr;
      if (MODE == 0 && region == 2) {
        const int row0_ = rowb + m * 16 + fq * 4;
        const int bI = row0_ >> 7, tl0 = row0_ & 127;
        const int c = col & 1023, h = c >> 6, d = c & 63;
        ushort4 pk;
        pk.x = f2bf(acc[m][n][0] + bv[n]);
        pk.y = f2bf(acc[m][n][1] + bv[n]);
        pk.z = f2bf(acc[m][n][2] + bv[n]);
        pk.w = f2bf(acc[m][n][3] + bv[n]);
        *(ushort4*)&O2[(((size_t)bI * 16 + h) * 64 + d) * 128 + tl0] = pk;
      } else {
#pragma unroll
        for (int j = 0; j < 4; ++j) {
          const int row = rowb + m * 16 + fq * 4 + j;
          float v = acc[m][n][j] + bv[n];
          if (MODE == 2) v = gelu_exact(v);
          if (MODE == 0) {
            const int bI = row >> 7, tl = row & 127;
            const int c = col & 1023, h = c >> 6, d = c & 63;
            if (region == 0) O0[(((size_t)bI * 16 + h) * 128 + tl) * 64 + d] = f2bf(v);
            else             O1[(((size_t)bI * 16 + h) * 128 + tl) * 64 + d] = f2bf(v);
          } else {
            O0[(size_t)row * N + col] = f2bf(v);
          }
        }
      }
    }
  }
}

// ---------------- fused attention: one block per (b,h), precomputed bf16 mask ----------------
__launch_bounds__(256)
__global__ void attn_kernel(const u16* __restrict__ Qg, const u16* __restrict__ Kg,
                            const u16* __restrict__ Vg,
                            const u16* __restrict__ mask,
                            u16* __restrict__ Og) {
  __shared__ u16 QK[2 * 128 * 64];
  __shared__ u16 Vt[64 * 128];
  const int tid = threadIdx.x;
  const int wv = tid >> 6;
  const int l = tid & 63;
  const int bh = blockIdx.x;
  const int b = bh >> 4;

  const char* Qs = (const char*)(Qg + (size_t)bh * 8192);
  const char* Ks = (const char*)(Kg + (size_t)bh * 8192);
  const char* Vs = (const char*)(Vg + (size_t)bh * 8192);
  char* QKb = (char*)QK;
  char* Vtb = (char*)Vt;
#pragma unroll
  for (int it = 0; it < 4; ++it) {
    const int r = it * 32 + (tid >> 3);
    const int cb = (tid & 7) * 16;
    const int sw = cb ^ ((r & 7) << 4);
    *(uint4*)(QKb + r * 128 + sw) = *(const uint4*)(Qs + r * 128 + cb);
    *(uint4*)(QKb + 16384 + r * 128 + sw) = *(const uint4*)(Ks + r * 128 + cb);
  }
#pragma unroll
  for (int it = 0; it < 4; ++it) {
    const int r = it * 16 + (tid >> 4);
    const int cb = (tid & 15) * 16;
    const int sw = cb ^ ((r & 7) << 4);
    *(uint4*)(Vtb + r * 256 + sw) = *(const uint4*)(Vs + r * 256 + cb);
  }
  __syncthreads();

  f32x4 s[2][8];
#pragma unroll
  for (int m = 0; m < 2; ++m)
#pragma unroll
    for (int n = 0; n < 8; ++n) s[m][n] = f32x4{0.f, 0.f, 0.f, 0.f};
#pragma unroll
  for (int kk = 0; kk < 2; ++kk) {
    bf16x8 qa[2], kb[8];
#pragma unroll
    for (int m = 0; m < 2; ++m) {
      const int qr = wv * 32 + m * 16 + (l & 15);
      qa[m] = *(const bf16x8*)(QKb + qr * 128 + ((kk * 64 + (l >> 4) * 16) ^ ((qr & 7) << 4)));
    }
#pragma unroll
    for (int n = 0; n < 8; ++n) {
      const int kr = n * 16 + (l & 15);
      kb[n] = *(const bf16x8*)(QKb + 16384 + kr * 128 + ((kk * 64 + (l >> 4) * 16) ^ ((kr & 7) << 4)));
    }
#pragma unroll
    for (int m = 0; m < 2; ++m)
#pragma unroll
      for (int n = 0; n < 8; ++n)
        s[m][n] = __builtin_amdgcn_mfma_f32_16x16x32_bf16(qa[m], kb[n], s[m][n], 0, 0, 0);
  }

  const u16* mbase = mask + (size_t)bh * 16384;
  float rinv[2][4];
#pragma unroll
  for (int m = 0; m < 2; ++m) {
#pragma unroll
    for (int j = 0; j < 4; ++j) {
      const int lq = wv * 32 + m * 16 + (l >> 4) * 4 + j;
      const u16* mrow = mbase + lq * 128 + (l & 15);
      float vals[8];
#pragma unroll
      for (int n = 0; n < 8; ++n)
        vals[n] = fmaf(s[m][n][j], 0.125f, bf2f(mrow[n * 16]));
      float mx = vals[0];
#pragma unroll
      for (int n = 1; n < 8; ++n) mx = fmaxf(mx, vals[n]);
#pragma unroll
      for (int o = 1; o < 16; o <<= 1) mx = fmaxf(mx, __shfl_xor(mx, o, 64));
      float sum = 0.f;
#pragma unroll
      for (int n = 0; n < 8; ++n) { vals[n] = expf(vals[n] - mx); sum += vals[n]; }
#pragma unroll
      for (int o = 1; o < 16; o <<= 1) sum += __shfl_xor(sum, o, 64);
      rinv[m][j] = 1.f / sum;
#pragma unroll
      for (int n = 0; n < 8; ++n) s[m][n][j] = vals[n];
    }
  }
  __syncthreads();
  char* Pb = QKb + wv * 8192;
#pragma unroll
  for (int m = 0; m < 2; ++m)
#pragma unroll
    for (int n = 0; n < 8; ++n)
#pragma unroll
      for (int j = 0; j < 4; ++j) {
        const int pr = m * 16 + (l >> 4) * 4 + j;
        const int pc = (n * 16 + (l & 15)) * 2;
        *(u16*)(Pb + pr * 256 + (pc ^ ((pr & 7) << 4))) = f2bf(s[m][n][j]);
      }
  __syncthreads();

  f32x4 o_[2][4];
#pragma unroll
  for (int m = 0; m < 2; ++m)
#pragma unroll
    for (int n = 0; n < 4; ++n) o_[m][n] = f32x4{0.f, 0.f, 0.f, 0.f};
#pragma unroll
  for (int ks = 0; ks < 4; ++ks) {
    bf16x8 pa[2], vb[4];
#pragma unroll
    for (int m = 0; m < 2; ++m) {
      const int pr = m * 16 + (l & 15);
      pa[m] = *(const bf16x8*)(Pb + pr * 256 + ((ks * 64 + (l >> 4) * 16) ^ ((pr & 7) << 4)));
    }
#pragma unroll
    for (int n = 0; n < 4; ++n) {
      const int vr = n * 16 + (l & 15);
      vb[n] = *(const bf16x8*)(Vtb + vr * 256 + ((ks * 64 + (l >> 4) * 16) ^ ((vr & 7) << 4)));
    }
#pragma unroll
    for (int m = 0; m < 2; ++m)
#pragma unroll
      for (int n = 0; n < 4; ++n)
        o_[m][n] = __builtin_amdgcn_mfma_f32_16x16x32_bf16(pa[m], vb[n], o_[m][n], 0, 0, 0);
  }
  const int h = bh & 15;
#pragma unroll
  for (int m = 0; m < 2; ++m)
#pragma unroll
    for (int n = 0; n < 4; ++n)
#pragma unroll
      for (int j = 0; j < 4; ++j) {
        const int lo2 = wv * 32 + m * 16 + (l >> 4) * 4 + j;
        const int d = n * 16 + (l & 15);
        Og[((size_t)b * 128 + lo2) * 1024 + h * 64 + d] = f2bf(o_[m][n][j] * rinv[m][j]);
      }
}

// ---------------- residual + LayerNorm, bf16 stream, vectorized ----------------
__launch_bounds__(256)
__global__ void ln_res(u16* __restrict__ xb, const u16* __restrict__ o,
                       const float* __restrict__ gam, const float* __restrict__ bet,
                       float* __restrict__ cls_out) {
  const int row = blockIdx.x * 4 + (threadIdx.x >> 6);
  const int l = threadIdx.x & 63;
  const size_t base = (size_t)row * 1024 + l * 16;
  const int c0 = l * 16;
  float v[16], gv[16], bb[16];
  float s = 0.f, sq = 0.f;
  const short8 xa = *(const short8*)(xb + base);
  const short8 xc = *(const short8*)(xb + base + 8);
  const short8 oa = *(const short8*)(o + base);
  const short8 oc = *(const short8*)(o + base + 8);
#pragma unroll
  for (int i = 0; i < 4; ++i) {
    *(float4*)&gv[i * 4] = *(const float4*)(gam + c0 + i * 4);
    *(float4*)&bb[i * 4] = *(const float4*)(bet + c0 + i * 4);
  }
#pragma unroll
  for (int i = 0; i < 8; ++i) {
    v[i] = bf2f((u16)xa[i]) + bf2f((u16)oa[i]);
    v[i + 8] = bf2f((u16)xc[i]) + bf2f((u16)oc[i]);
  }
#pragma unroll
  for (int i = 0; i < 16; ++i) { s += v[i]; sq += v[i] * v[i]; }
#pragma unroll
  for (int off = 1; off < 64; off <<= 1) {
    s += __shfl_xor(s, off, 64);
    sq += __shfl_xor(sq, off, 64);
  }
  const float mean = s * (1.f / 1024.f);
  const float var = sq * (1.f / 1024.f) - mean * mean;
  const float rstd = rsqrtf(var + 1e-5f);
  short8 ra, rc;
#pragma unroll
  for (int i = 0; i < 8; ++i) {
    const float ya = (v[i] - mean) * rstd * gv[i] + bb[i];
    const float yc = (v[i + 8] - mean) * rstd * gv[i + 8] + bb[i + 8];
    ra[i] = (short)f2bf(ya);
    rc[i] = (short)f2bf(yc);
    if ((row & 127) == 0) {
      cls_out[(size_t)(row >> 7) * 1024 + c0 + i] = ya;
      cls_out[(size_t)(row >> 7) * 1024 + c0 + 8 + i] = yc;
    }
  }
  *(short8*)(xb + base) = ra;
  *(short8*)(xb + base + 8) = rc;
}

extern "C" void kernel_launch(void* const* d_in, const int* in_sizes, int n_in,
                              void* d_out, int out_size, void* d_ws, size_t ws_size,
                              hipStream_t stream) {
  const int* z = (const int*)d_in[0];
  const int* hgs = (const int*)d_in[1];
  const float* pos = (const float*)d_in[2];
  const float* atoms_emb = (const float*)d_in[4];
  const float* neigh_emb = (const float*)d_in[5];
  const float* dist_emb = (const float*)d_in[6];
  const float* Wqkv = (const float*)d_in[7];
  const float* bqkv = (const float*)d_in[8];
  const float* Wo = (const float*)d_in[9];
  const float* bo = (const float*)d_in[10];
  const float* W1 = (const float*)d_in[11];
  const float* b1f = (const float*)d_in[12];
  const float* W2 = (const float*)d_in[13];
  const float* b2f = (const float*)d_in[14];
  const float* ln1g = (const float*)d_in[15];
  const float* ln1b = (const float*)d_in[16];
  const float* ln2g = (const float*)d_in[17];
  const float* ln2b = (const float*)d_in[18];

  size_t off = 0;
  char* wsb = (char*)d_ws;
  auto alc = [&](size_t bytes) { void* p = wsb + off; off += (bytes + 255) & ~(size_t)255; return p; };
  u16* xb = (u16*)alc(8192ull * 1024 * 2);
  u16* q = (u16*)alc(8192ull * 1024 * 2);
  u16* k = (u16*)alc(8192ull * 1024 * 2);
  u16* v = (u16*)alc(8192ull * 1024 * 2);
  u16* big = (u16*)alc(8192ull * 3072 * 2);
  u16* proj = (u16*)alc(8192ull * 1024 * 2);
  u16* wqkvt = (u16*)alc(3072ull * 1024 * 2);
  u16* wot = (u16*)alc(1024ull * 1024 * 2);
  u16* w1t = (u16*)alc(3072ull * 1024 * 2);
  u16* w2t = (u16*)alc(1024ull * 3072 * 2);
  u16* mask = (u16*)alc(64ull * 16 * 128 * 128 * 2);

  hipFuncSetAttribute((const void*)gemmP<0, 2>, hipFuncAttributeMaxDynamicSharedMemorySize, 73728);
  hipFuncSetAttribute((const void*)gemmP<2, 2>, hipFuncAttributeMaxDynamicSharedMemorySize, 73728);
  hipFuncSetAttribute((const void*)gemmP<1, 1>, hipFuncAttributeMaxDynamicSharedMemorySize, 49152);

  transpose_w<<<dim3(96, 32), dim3(32, 8), 0, stream>>>(Wqkv, wqkvt, 1024, 3072);
  transpose_w<<<dim3(32, 32), dim3(32, 8), 0, stream>>>(Wo, wot, 1024, 1024);
  transpose_w<<<dim3(96, 32), dim3(32, 8), 0, stream>>>(W1, w1t, 1024, 3072);
  transpose_w<<<dim3(32, 96), dim3(32, 8), 0, stream>>>(W2, w2t, 3072, 1024);
  embed_k<<<8192, 256, 0, stream>>>(z, hgs, atoms_emb, neigh_emb, xb);
  mask_k<<<8192, 128, 0, stream>>>(pos, dist_emb, mask);

  float* cls = (float*)d_out;
  for (int layer = 0; layer < 8; ++layer) {
    gemmP<0, 2><<<768, 256, 73728, stream>>>(xb, wqkvt, bqkv, q, k, v, 3072, 1024);
    attn_kernel<<<1024, 256, 0, stream>>>(q, k, v, mask, big);
    gemmP<1, 1><<<512, 256, 49152, stream>>>(big, wot, bo, proj, nullptr, nullptr, 1024, 1024);
    ln_res<<<2048, 256, 0, stream>>>(xb, proj, ln1g, ln1b, cls);
    gemmP<2, 2><<<768, 256, 73728, stream>>>(xb, w1t, b1f, big, nullptr, nullptr, 3072, 1024);
    gemmP<1, 1><<<512, 256, 49152, stream>>>(big, w2t, b2f, proj, nullptr, nullptr, 1024, 3072);
    ln_res<<<2048, 256, 0, stream>>>(xb, proj, ln2g, ln2b, cls);
  }
}

// Round 7
// 2315.155 us; speedup vs baseline: 1.2650x; 1.0288x over previous
//
#include <hip/hip_runtime.h>
#include <cstdint>
#include <math.h>

typedef unsigned short u16;
typedef __attribute__((ext_vector_type(4))) float f32x4;
typedef __attribute__((ext_vector_type(8))) __bf16 bf16x8;
typedef __attribute__((ext_vector_type(8))) short short8;

typedef __attribute__((address_space(1))) void g_void;
typedef __attribute__((address_space(3))) void l_void;

__device__ __forceinline__ u16 f2bf(float f) {
  uint32_t u = __builtin_bit_cast(uint32_t, f);
  u += 0x7FFFu + ((u >> 16) & 1u);
  return (u16)(u >> 16);
}
__device__ __forceinline__ float bf2f(u16 h) {
  uint32_t u = ((uint32_t)h) << 16;
  return __builtin_bit_cast(float, u);
}

__device__ __forceinline__ void gload16(const void* g, void* l) {
  __builtin_amdgcn_global_load_lds((g_void*)g, (l_void*)l, 16, 0, 0);
}

// branchless GELU: erf via A&S 7.1.26 (max abs err 1.5e-7)
__device__ __forceinline__ float gelu_exact(float x) {
  float a = x * 0.70710678118654752f;
  float s = fabsf(a);
  float t = __builtin_amdgcn_rcpf(fmaf(0.3275911f, s, 1.0f));
  float p = fmaf(fmaf(fmaf(fmaf(1.061405429f, t, -1.453152027f), t, 1.421413741f), t,
                      -0.284496736f), t, 0.254829592f);
  p *= t;
  float e = __expf(-s * s);
  float er = fmaf(-p, e, 1.0f);
  er = copysignf(er, a);
  return 0.5f * x * (1.0f + er);
}

// ---------------- weight transpose + bf16 convert: Wt[n][k] = W[k][n] ----------------
__global__ void transpose_w(const float* __restrict__ W, u16* __restrict__ Wt, int K, int N) {
  __shared__ float t[32][33];
  const int nb = blockIdx.x * 32, kb = blockIdx.y * 32;
  const int tx = threadIdx.x, ty = threadIdx.y;
#pragma unroll
  for (int i = 0; i < 32; i += 8)
    t[ty + i][tx] = W[(size_t)(kb + ty + i) * N + nb + tx];
  __syncthreads();
#pragma unroll
  for (int i = 0; i < 32; i += 8)
    Wt[(size_t)(nb + ty + i) * K + kb + tx] = f2bf(t[tx][ty + i]);
}

// ---------------- embedding (bf16 residual stream) ----------------
__global__ void embed_k(const int* __restrict__ z, const int* __restrict__ hgs,
                        const float* __restrict__ ae, const float* __restrict__ ne,
                        u16* __restrict__ xb) {
  const int row = blockIdx.x;
  const int b = row >> 7, tl = row & 127;
  int ia = 1, in_ = 0;
  if (tl > 0) { ia = z[b * 127 + tl - 1] + 2; in_ = hgs[b * 127 + tl - 1] + 2; }
  const float* ar = ae + (size_t)ia * 1024;
  const float* nr = ne + (size_t)in_ * 1024;
  for (int c = threadIdx.x; c < 1024; c += 256)
    xb[(size_t)row * 1024 + c] = f2bf(ar[c] + nr[c]);
}

// ---------------- attention bias mask precompute: (B,H,128,128) bf16 ----------------
__global__ void mask_k(const float* __restrict__ pos, const float* __restrict__ demb,
                       u16* __restrict__ mask) {
  __shared__ float edges[85];
  __shared__ float dh[86 * 16];
  const int bq = blockIdx.x;
  const int b = bq >> 7, lq = bq & 127;
  const int lk = threadIdx.x;  // 128 threads
  if (lk < 85) {
    double e = 0.75 + 0.05 * (double)lk;
    float ef = (float)e;
    if (lk == 0) ef = -1.0f; else if (lk == 1) ef = 0.0f; else if (lk == 2) ef = 0.01f;
    edges[lk] = ef;
  }
  for (int i = lk; i < 86 * 16; i += 128) {
    float v = demb[i];
    if (i < 16) v = -INFINITY;
    dh[i] = v;
  }
  __syncthreads();
  int c;
  if (lq == 0 || lk == 0) {
    c = 1;
  } else {
    const float* pi = pos + ((size_t)b * 127 + lq - 1) * 3;
    const float* pj = pos + ((size_t)b * 127 + lk - 1) * 3;
    const float dx = pi[0] - pj[0], dy = pi[1] - pj[1], dz = pi[2] - pj[2];
    const float d = sqrtf(dx * dx + dy * dy + dz * dz);
    int cnt = 0;
#pragma unroll
    for (int k2 = 0; k2 < 85; ++k2) cnt += (edges[k2] <= d) ? 1 : 0;
    c = cnt;
  }
#pragma unroll
  for (int h = 0; h < 16; ++h)
    mask[(((size_t)b * 16 + h) * 128 + lq) * 128 + lk] = f2bf(dh[c * 16 + h]);
}

// ------- GEMM: 512 thr, 8 waves (4Mx2N), BM=256 BN=128 BK=32, wave-tile 64x64 --------
// 3-buf depth-2 counted vmcnt; st-swizzled LDS; 2 blocks/CU -> 4 waves/SIMD.
// MODE 0: qkv scatter  MODE 2: gelu bf16  MODE 3: f32 partial (split-K, no bias)
// grid = ntiles * nsplit; ntiles = (M/256)*(N/128); split s works K range [s*kLen, (s+1)*kLen)
template <int MODE>
__launch_bounds__(512, 4)
__global__ void gemmS(const u16* __restrict__ A, const u16* __restrict__ Bt,
                      const float* __restrict__ bias,
                      u16* __restrict__ O0, u16* __restrict__ O1, u16* __restrict__ O2,
                      float* __restrict__ Pout,
                      int N, int K, int ntiles, int kLen) {
  extern __shared__ char lds[];
  constexpr int SLAB = 24576;  // A 256x32 (16KB) + B 128x32 (8KB)
  const int tid = threadIdx.x;
  const int w = tid >> 6, l = tid & 63;
  const int wr = w >> 1, wc = w & 1;
  // bijective XCD swizzle (grid % 8 == 0 always here)
  const int nwg = gridDim.x;
  const int wg = (blockIdx.x & 7) * (nwg >> 3) + (blockIdx.x >> 3);
  const int s = wg / ntiles;
  const int tile = wg - s * ntiles;
  const int ntn = N >> 7;
  const int bm = tile / ntn, bn = tile - (tile / ntn) * ntn;
  const int kStart = s * kLen;
  const int NT = kLen >> 5;

  // staging: call covers 128 rows; row = w*16 + (l>>2); inverse st-swizzle on source col
  const int colc = ((((l & 3) << 4) ^ (((l >> 2) & 8) << 2)) >> 1);
  const u16* Ag = A + (size_t)(bm * 256 + w * 16 + (l >> 2)) * K + kStart + colc;
  const u16* Bg = Bt + (size_t)(bn * 128 + w * 16 + (l >> 2)) * K + kStart + colc;
  const int ldst = w << 10;

  auto stage = [&](int t, char* buf) {
    const int kb = t << 5;
    gload16(Ag + kb, buf + ldst);                       // A rows 0..127
    gload16(Ag + (size_t)128 * K + kb, buf + 8192 + ldst);  // A rows 128..255
    gload16(Bg + kb, buf + 16384 + ldst);               // B rows 0..127
  };

  // swizzled fragment read offset within a 1KB subtile (16 rows x 64B)
  const int lo = ((l & 15) << 6) + (((l >> 4) << 4) ^ ((l & 8) << 2));

  f32x4 acc[4][4];
#pragma unroll
  for (int m = 0; m < 4; ++m)
#pragma unroll
    for (int n = 0; n < 4; ++n) acc[m][n] = f32x4{0.f, 0.f, 0.f, 0.f};

  char* p0 = lds;
  char* p1 = lds + SLAB;
  char* p2 = lds + 2 * SLAB;

  stage(0, p0);
  stage(1, p1);
  asm volatile("s_waitcnt vmcnt(3)" ::: "memory");
  __builtin_amdgcn_s_barrier();

  for (int t = 0; t < NT; ++t) {
    if (t + 2 < NT) stage(t + 2, p2);
    const char* ab = p0 + (wr << 12);          // wave's 64 A-rows
    const char* bb = p0 + 16384 + (wc << 12);  // wave's 64 B-rows
    bf16x8 af[4], bf[4];
#pragma unroll
    for (int m = 0; m < 4; ++m) af[m] = *(const bf16x8*)(ab + (m << 10) + lo);
#pragma unroll
    for (int n = 0; n < 4; ++n) bf[n] = *(const bf16x8*)(bb + (n << 10) + lo);
    __builtin_amdgcn_s_setprio(1);
#pragma unroll
    for (int m = 0; m < 4; ++m)
#pragma unroll
      for (int n = 0; n < 4; ++n)
        acc[m][n] = __builtin_amdgcn_mfma_f32_16x16x32_bf16(af[m], bf[n], acc[m][n], 0, 0, 0);
    __builtin_amdgcn_s_setprio(0);
    if (t + 2 < NT) asm volatile("s_waitcnt vmcnt(3)" ::: "memory");
    else            asm volatile("s_waitcnt vmcnt(0)" ::: "memory");
    __builtin_amdgcn_s_barrier();
    char* tmp = p0; p0 = p1; p1 = p2; p2 = tmp;
  }

  // epilogue: wave covers rows rowb..+63, cols colb..+63
  const int fr = l & 15, fq = l >> 4;
  const int colb = bn * 128 + wc * 64;
  const int rowb = bm * 256 + wr * 64;
  float bv[4];
  if (MODE != 3) {
#pragma unroll
    for (int n = 0; n < 4; ++n) bv[n] = bias[colb + n * 16 + fr];
  }
  const int region = colb >> 10;

#pragma unroll
  for (int m = 0; m < 4; ++m) {
#pragma unroll
    for (int n = 0; n < 4; ++n) {
      const int col = colb + n * 16 + fr;
      if (MODE == 0 && region == 2) {
        const int row0_ = rowb + m * 16 + fq * 4;
        const int bI = row0_ >> 7, tl0 = row0_ & 127;
        const int c = col & 1023, h = c >> 6, d = c & 63;
        ushort4 pk;
        pk.x = f2bf(acc[m][n][0] + bv[n]);
        pk.y = f2bf(acc[m][n][1] + bv[n]);
        pk.z = f2bf(acc[m][n][2] + bv[n]);
        pk.w = f2bf(acc[m][n][3] + bv[n]);
        *(ushort4*)&O2[(((size_t)bI * 16 + h) * 64 + d) * 128 + tl0] = pk;
      } else {
#pragma unroll
        for (int j = 0; j < 4; ++j) {
          const int row = rowb + m * 16 + fq * 4 + j;
          if (MODE == 3) {
            Pout[(size_t)s * 8388608 + (size_t)row * N + col] = acc[m][n][j];
          } else {
            float v = acc[m][n][j] + bv[n];
            if (MODE == 2) v = gelu_exact(v);
            if (MODE == 0) {
              const int bI = row >> 7, tl = row & 127;
              const int c = col & 1023, h = c >> 6, d = c & 63;
              if (region == 0) O0[(((size_t)bI * 16 + h) * 128 + tl) * 64 + d] = f2bf(v);
              else             O1[(((size_t)bI * 16 + h) * 128 + tl) * 64 + d] = f2bf(v);
            } else {
              O0[(size_t)row * N + col] = f2bf(v);
            }
          }
        }
      }
    }
  }
}

// ---------------- fused attention: one block per (b,h), precomputed bf16 mask ----------------
__launch_bounds__(256)
__global__ void attn_kernel(const u16* __restrict__ Qg, const u16* __restrict__ Kg,
                            const u16* __restrict__ Vg,
                            const u16* __restrict__ mask,
                            u16* __restrict__ Og) {
  __shared__ u16 QK[2 * 128 * 64];
  __shared__ u16 Vt[64 * 128];
  const int tid = threadIdx.x;
  const int wv = tid >> 6;
  const int l = tid & 63;
  const int bh = blockIdx.x;
  const int b = bh >> 4;

  const char* Qs = (const char*)(Qg + (size_t)bh * 8192);
  const char* Ks = (const char*)(Kg + (size_t)bh * 8192);
  const char* Vs = (const char*)(Vg + (size_t)bh * 8192);
  char* QKb = (char*)QK;
  char* Vtb = (char*)Vt;
#pragma unroll
  for (int it = 0; it < 4; ++it) {
    const int r = it * 32 + (tid >> 3);
    const int cb = (tid & 7) * 16;
    const int sw = cb ^ ((r & 7) << 4);
    *(uint4*)(QKb + r * 128 + sw) = *(const uint4*)(Qs + r * 128 + cb);
    *(uint4*)(QKb + 16384 + r * 128 + sw) = *(const uint4*)(Ks + r * 128 + cb);
  }
#pragma unroll
  for (int it = 0; it < 4; ++it) {
    const int r = it * 16 + (tid >> 4);
    const int cb = (tid & 15) * 16;
    const int sw = cb ^ ((r & 7) << 4);
    *(uint4*)(Vtb + r * 256 + sw) = *(const uint4*)(Vs + r * 256 + cb);
  }
  __syncthreads();

  f32x4 s[2][8];
#pragma unroll
  for (int m = 0; m < 2; ++m)
#pragma unroll
    for (int n = 0; n < 8; ++n) s[m][n] = f32x4{0.f, 0.f, 0.f, 0.f};
#pragma unroll
  for (int kk = 0; kk < 2; ++kk) {
    bf16x8 qa[2], kb[8];
#pragma unroll
    for (int m = 0; m < 2; ++m) {
      const int qr = wv * 32 + m * 16 + (l & 15);
      qa[m] = *(const bf16x8*)(QKb + qr * 128 + ((kk * 64 + (l >> 4) * 16) ^ ((qr & 7) << 4)));
    }
#pragma unroll
    for (int n = 0; n < 8; ++n) {
      const int kr = n * 16 + (l & 15);
      kb[n] = *(const bf16x8*)(QKb + 16384 + kr * 128 + ((kk * 64 + (l >> 4) * 16) ^ ((kr & 7) << 4)));
    }
#pragma unroll
    for (int m = 0; m < 2; ++m)
#pragma unroll
      for (int n = 0; n < 8; ++n)
        s[m][n] = __builtin_amdgcn_mfma_f32_16x16x32_bf16(qa[m], kb[n], s[m][n], 0, 0, 0);
  }

  const u16* mbase = mask + (size_t)bh * 16384;
  float rinv[2][4];
#pragma unroll
  for (int m = 0; m < 2; ++m) {
#pragma unroll
    for (int j = 0; j < 4; ++j) {
      const int lq = wv * 32 + m * 16 + (l >> 4) * 4 + j;
      const u16* mrow = mbase + lq * 128 + (l & 15);
      float vals[8];
#pragma unroll
      for (int n = 0; n < 8; ++n)
        vals[n] = fmaf(s[m][n][j], 0.125f, bf2f(mrow[n * 16]));
      float mx = vals[0];
#pragma unroll
      for (int n = 1; n < 8; ++n) mx = fmaxf(mx, vals[n]);
#pragma unroll
      for (int o = 1; o < 16; o <<= 1) mx = fmaxf(mx, __shfl_xor(mx, o, 64));
      float sum = 0.f;
#pragma unroll
      for (int n = 0; n < 8; ++n) { vals[n] = expf(vals[n] - mx); sum += vals[n]; }
#pragma unroll
      for (int o = 1; o < 16; o <<= 1) sum += __shfl_xor(sum, o, 64);
      rinv[m][j] = 1.f / sum;
#pragma unroll
      for (int n = 0; n < 8; ++n) s[m][n][j] = vals[n];
    }
  }
  __syncthreads();
  char* Pb = QKb + wv * 8192;
#pragma unroll
  for (int m = 0; m < 2; ++m)
#pragma unroll
    for (int n = 0; n < 8; ++n)
#pragma unroll
      for (int j = 0; j < 4; ++j) {
        const int pr = m * 16 + (l >> 4) * 4 + j;
        const int pc = (n * 16 + (l & 15)) * 2;
        *(u16*)(Pb + pr * 256 + (pc ^ ((pr & 7) << 4))) = f2bf(s[m][n][j]);
      }
  __syncthreads();

  f32x4 o_[2][4];
#pragma unroll
  for (int m = 0; m < 2; ++m)
#pragma unroll
    for (int n = 0; n < 4; ++n) o_[m][n] = f32x4{0.f, 0.f, 0.f, 0.f};
#pragma unroll
  for (int ks = 0; ks < 4; ++ks) {
    bf16x8 pa[2], vb[4];
#pragma unroll
    for (int m = 0; m < 2; ++m) {
      const int pr = m * 16 + (l & 15);
      pa[m] = *(const bf16x8*)(Pb + pr * 256 + ((ks * 64 + (l >> 4) * 16) ^ ((pr & 7) << 4)));
    }
#pragma unroll
    for (int n = 0; n < 4; ++n) {
      const int vr = n * 16 + (l & 15);
      vb[n] = *(const bf16x8*)(Vtb + vr * 256 + ((ks * 64 + (l >> 4) * 16) ^ ((vr & 7) << 4)));
    }
#pragma unroll
    for (int m = 0; m < 2; ++m)
#pragma unroll
      for (int n = 0; n < 4; ++n)
        o_[m][n] = __builtin_amdgcn_mfma_f32_16x16x32_bf16(pa[m], vb[n], o_[m][n], 0, 0, 0);
  }
  const int h = bh & 15;
#pragma unroll
  for (int m = 0; m < 2; ++m)
#pragma unroll
    for (int n = 0; n < 4; ++n)
#pragma unroll
      for (int j = 0; j < 4; ++j) {
        const int lo2 = wv * 32 + m * 16 + (l >> 4) * 4 + j;
        const int d = n * 16 + (l & 15);
        Og[((size_t)b * 128 + lo2) * 1024 + h * 64 + d] = f2bf(o_[m][n][j] * rinv[m][j]);
      }
}

// ------- residual + LN fused with split-K reduce: x + (p0 + p1 + bias) -> LN -> xb ------
__launch_bounds__(256)
__global__ void ln_resS(u16* __restrict__ xb, const float* __restrict__ P,
                        const float* __restrict__ bias,
                        const float* __restrict__ gam, const float* __restrict__ bet,
                        float* __restrict__ cls_out) {
  const int row = blockIdx.x * 4 + (threadIdx.x >> 6);
  const int l = threadIdx.x & 63;
  const size_t base = (size_t)row * 1024 + l * 16;
  const int c0 = l * 16;
  float v[16], gv[16], bb[16], bi[16], pa[16], pb[16];
  const short8 xa = *(const short8*)(xb + base);
  const short8 xc = *(const short8*)(xb + base + 8);
#pragma unroll
  for (int i = 0; i < 4; ++i) {
    *(float4*)&pa[i * 4] = *(const float4*)(P + base + i * 4);
    *(float4*)&pb[i * 4] = *(const float4*)(P + 8388608 + base + i * 4);
    *(float4*)&gv[i * 4] = *(const float4*)(gam + c0 + i * 4);
    *(float4*)&bb[i * 4] = *(const float4*)(bet + c0 + i * 4);
    *(float4*)&bi[i * 4] = *(const float4*)(bias + c0 + i * 4);
  }
  float s = 0.f, sq = 0.f;
#pragma unroll
  for (int i = 0; i < 8; ++i) {
    v[i] = bf2f((u16)xa[i]) + pa[i] + pb[i] + bi[i];
    v[i + 8] = bf2f((u16)xc[i]) + pa[i + 8] + pb[i + 8] + bi[i + 8];
  }
#pragma unroll
  for (int i = 0; i < 16; ++i) { s += v[i]; sq += v[i] * v[i]; }
#pragma unroll
  for (int off = 1; off < 64; off <<= 1) {
    s += __shfl_xor(s, off, 64);
    sq += __shfl_xor(sq, off, 64);
  }
  const float mean = s * (1.f / 1024.f);
  const float var = sq * (1.f / 1024.f) - mean * mean;
  const float rstd = rsqrtf(var + 1e-5f);
  short8 ra, rc;
#pragma unroll
  for (int i = 0; i < 8; ++i) {
    const float ya = (v[i] - mean) * rstd * gv[i] + bb[i];
    const float yc = (v[i + 8] - mean) * rstd * gv[i + 8] + bb[i + 8];
    ra[i] = (short)f2bf(ya);
    rc[i] = (short)f2bf(yc);
    if ((row & 127) == 0) {
      cls_out[(size_t)(row >> 7) * 1024 + c0 + i] = ya;
      cls_out[(size_t)(row >> 7) * 1024 + c0 + 8 + i] = yc;
    }
  }
  *(short8*)(xb + base) = ra;
  *(short8*)(xb + base + 8) = rc;
}

extern "C" void kernel_launch(void* const* d_in, const int* in_sizes, int n_in,
                              void* d_out, int out_size, void* d_ws, size_t ws_size,
                              hipStream_t stream) {
  const int* z = (const int*)d_in[0];
  const int* hgs = (const int*)d_in[1];
  const float* pos = (const float*)d_in[2];
  const float* atoms_emb = (const float*)d_in[4];
  const float* neigh_emb = (const float*)d_in[5];
  const float* dist_emb = (const float*)d_in[6];
  const float* Wqkv = (const float*)d_in[7];
  const float* bqkv = (const float*)d_in[8];
  const float* Wo = (const float*)d_in[9];
  const float* bo = (const float*)d_in[10];
  const float* W1 = (const float*)d_in[11];
  const float* b1f = (const float*)d_in[12];
  const float* W2 = (const float*)d_in[13];
  const float* b2f = (const float*)d_in[14];
  const float* ln1g = (const float*)d_in[15];
  const float* ln1b = (const float*)d_in[16];
  const float* ln2g = (const float*)d_in[17];
  const float* ln2b = (const float*)d_in[18];

  size_t off = 0;
  char* wsb = (char*)d_ws;
  auto alc = [&](size_t bytes) { void* p = wsb + off; off += (bytes + 255) & ~(size_t)255; return p; };
  u16* xb = (u16*)alc(8192ull * 1024 * 2);
  u16* q = (u16*)alc(8192ull * 1024 * 2);   // p0 spans q+k (f32 8192x1024)
  u16* k = (u16*)alc(8192ull * 1024 * 2);
  u16* v = (u16*)alc(8192ull * 1024 * 2);   // p1 spans v+proj
  u16* proj = (u16*)alc(8192ull * 1024 * 2);
  u16* big = (u16*)alc(8192ull * 3072 * 2);
  u16* wqkvt = (u16*)alc(3072ull * 1024 * 2);
  u16* wot = (u16*)alc(1024ull * 1024 * 2);
  u16* w1t = (u16*)alc(3072ull * 1024 * 2);
  u16* w2t = (u16*)alc(1024ull * 3072 * 2);
  u16* mask = (u16*)alc(64ull * 16 * 128 * 128 * 2);
  float* pp = (float*)q;  // split-K partials: [2][8192][1024] f32 over q,k,v,proj
  (void)proj;

  hipFuncSetAttribute((const void*)gemmS<0>, hipFuncAttributeMaxDynamicSharedMemorySize, 73728);
  hipFuncSetAttribute((const void*)gemmS<2>, hipFuncAttributeMaxDynamicSharedMemorySize, 73728);
  hipFuncSetAttribute((const void*)gemmS<3>, hipFuncAttributeMaxDynamicSharedMemorySize, 73728);

  transpose_w<<<dim3(96, 32), dim3(32, 8), 0, stream>>>(Wqkv, wqkvt, 1024, 3072);
  transpose_w<<<dim3(32, 32), dim3(32, 8), 0, stream>>>(Wo, wot, 1024, 1024);
  transpose_w<<<dim3(96, 32), dim3(32, 8), 0, stream>>>(W1, w1t, 1024, 3072);
  transpose_w<<<dim3(32, 96), dim3(32, 8), 0, stream>>>(W2, w2t, 3072, 1024);
  embed_k<<<8192, 256, 0, stream>>>(z, hgs, atoms_emb, neigh_emb, xb);
  mask_k<<<8192, 128, 0, stream>>>(pos, dist_emb, mask);

  float* cls = (float*)d_out;
  for (int layer = 0; layer < 8; ++layer) {
    // QKV: M=8192 N=3072 K=1024, ntiles=32x24=768, no split
    gemmS<0><<<768, 512, 73728, stream>>>(xb, wqkvt, bqkv, q, k, v, nullptr, 3072, 1024, 768, 1024);
    attn_kernel<<<1024, 256, 0, stream>>>(q, k, v, mask, big);
    // o-proj: N=1024 K=1024, ntiles=32x8=256, split 2 x K=512 -> f32 partials
    gemmS<3><<<512, 512, 73728, stream>>>(big, wot, nullptr, nullptr, nullptr, nullptr, pp, 1024, 1024, 256, 512);
    ln_resS<<<2048, 256, 0, stream>>>(xb, pp, bo, ln1g, ln1b, cls);
    // FF1: N=3072 K=1024 + GELU
    gemmS<2><<<768, 512, 73728, stream>>>(xb, w1t, b1f, big, nullptr, nullptr, nullptr, 3072, 1024, 768, 1024);
    // FF2: N=1024 K=3072, split 2 x K=1536
    gemmS<3><<<512, 512, 73728, stream>>>(big, w2t, nullptr, nullptr, nullptr, nullptr, pp, 1024, 3072, 256, 1536);
    ln_resS<<<2048, 256, 0, stream>>>(xb, pp, b2f, ln2g, ln2b, cls);
  }
}

// Round 9
// 2210.780 us; speedup vs baseline: 1.3247x; 1.0472x over previous
//
#include <hip/hip_runtime.h>
#include <cstdint>
#include <math.h>

typedef unsigned short u16;
typedef __attribute__((ext_vector_type(4))) float f32x4;
typedef __attribute__((ext_vector_type(8))) __bf16 bf16x8;
typedef __attribute__((ext_vector_type(8))) short short8;

typedef __attribute__((address_space(1))) void g_void;
typedef __attribute__((address_space(3))) void l_void;

__device__ __forceinline__ u16 f2bf(float f) {
  uint32_t u = __builtin_bit_cast(uint32_t, f);
  u += 0x7FFFu + ((u >> 16) & 1u);
  return (u16)(u >> 16);
}
__device__ __forceinline__ float bf2f(u16 h) {
  uint32_t u = ((uint32_t)h) << 16;
  return __builtin_bit_cast(float, u);
}

__device__ __forceinline__ void gload16(const void* g, void* l) {
  __builtin_amdgcn_global_load_lds((g_void*)g, (l_void*)l, 16, 0, 0);
}

// branchless GELU: erf via A&S 7.1.26 (max abs err 1.5e-7)
__device__ __forceinline__ float gelu_exact(float x) {
  float a = x * 0.70710678118654752f;
  float s = fabsf(a);
  float t = __builtin_amdgcn_rcpf(fmaf(0.3275911f, s, 1.0f));
  float p = fmaf(fmaf(fmaf(fmaf(1.061405429f, t, -1.453152027f), t, 1.421413741f), t,
                      -0.284496736f), t, 0.254829592f);
  p *= t;
  float e = __expf(-s * s);
  float er = fmaf(-p, e, 1.0f);
  er = copysignf(er, a);
  return 0.5f * x * (1.0f + er);
}

// ---------------- weight transpose + bf16 convert: Wt[n][k] = W[k][n] ----------------
__global__ void transpose_w(const float* __restrict__ W, u16* __restrict__ Wt, int K, int N) {
  __shared__ float t[32][33];
  const int nb = blockIdx.x * 32, kb = blockIdx.y * 32;
  const int tx = threadIdx.x, ty = threadIdx.y;
#pragma unroll
  for (int i = 0; i < 32; i += 8)
    t[ty + i][tx] = W[(size_t)(kb + ty + i) * N + nb + tx];
  __syncthreads();
#pragma unroll
  for (int i = 0; i < 32; i += 8)
    Wt[(size_t)(nb + ty + i) * K + kb + tx] = f2bf(t[tx][ty + i]);
}

// ---------------- embedding (bf16 residual stream) ----------------
__global__ void embed_k(const int* __restrict__ z, const int* __restrict__ hgs,
                        const float* __restrict__ ae, const float* __restrict__ ne,
                        u16* __restrict__ xb) {
  const int row = blockIdx.x;
  const int b = row >> 7, tl = row & 127;
  int ia = 1, in_ = 0;
  if (tl > 0) { ia = z[b * 127 + tl - 1] + 2; in_ = hgs[b * 127 + tl - 1] + 2; }
  const float* ar = ae + (size_t)ia * 1024;
  const float* nr = ne + (size_t)in_ * 1024;
  for (int c = threadIdx.x; c < 1024; c += 256)
    xb[(size_t)row * 1024 + c] = f2bf(ar[c] + nr[c]);
}

// ------- attention bias mask precompute, layout [b][h][fr:16][lq:128][n:8] bf16 -------
// so attn thread (lane fr) reads its 8 per-row values as one 16B load
__global__ void mask_k(const float* __restrict__ pos, const float* __restrict__ demb,
                       u16* __restrict__ mask) {
  __shared__ float edges[85];
  __shared__ float dh[86 * 16];
  const int bq = blockIdx.x;
  const int b = bq >> 7, lq = bq & 127;
  const int lk = threadIdx.x;  // 128 threads
  if (lk < 85) {
    double e = 0.75 + 0.05 * (double)lk;
    float ef = (float)e;
    if (lk == 0) ef = -1.0f; else if (lk == 1) ef = 0.0f; else if (lk == 2) ef = 0.01f;
    edges[lk] = ef;
  }
  for (int i = lk; i < 86 * 16; i += 128) {
    float v = demb[i];
    if (i < 16) v = -INFINITY;
    dh[i] = v;
  }
  __syncthreads();
  int c;
  if (lq == 0 || lk == 0) {
    c = 1;
  } else {
    const float* pi = pos + ((size_t)b * 127 + lq - 1) * 3;
    const float* pj = pos + ((size_t)b * 127 + lk - 1) * 3;
    const float dx = pi[0] - pj[0], dy = pi[1] - pj[1], dz = pi[2] - pj[2];
    const float d = sqrtf(dx * dx + dy * dy + dz * dz);
    int cnt = 0;
#pragma unroll
    for (int k2 = 0; k2 < 85; ++k2) cnt += (edges[k2] <= d) ? 1 : 0;
    c = cnt;
  }
  const int fr = lk & 15, nn = lk >> 4;
#pragma unroll
  for (int h = 0; h < 16; ++h)
    mask[((((size_t)(b * 16 + h) * 16 + fr) * 128 + lq) << 3) + nn] = f2bf(dh[c * 16 + h]);
}

// ------- big GEMM: 512 thr, 8 waves (4Mx2N), BM=256 BN=128 BK=32, wave-tile 64x64 -----
// 3-buf depth-2 counted vmcnt; st-swizzled LDS; 2 blocks/CU -> 4 waves/SIMD.
// MODE 0: qkv scatter -> Q(B,H,L,d) K(B,H,L,d) V(B,H,d,L)   MODE 2: gelu bf16
template <int MODE>
__launch_bounds__(512, 4)
__global__ void gemmS(const u16* __restrict__ A, const u16* __restrict__ Bt,
                      const float* __restrict__ bias,
                      u16* __restrict__ O0, u16* __restrict__ O1, u16* __restrict__ O2,
                      int N, int K) {
  extern __shared__ char lds[];
  constexpr int SLAB = 24576;  // A 256x32 (16KB) + B 128x32 (8KB)
  const int tid = threadIdx.x;
  const int w = tid >> 6, l = tid & 63;
  const int wr = w >> 1, wc = w & 1;
  const int nwg = gridDim.x;
  const int wg = (blockIdx.x & 7) * (nwg >> 3) + (blockIdx.x >> 3);
  const int ntn = N >> 7;
  const int bm = wg / ntn, bn = wg - (wg / ntn) * ntn;
  const int NT = K >> 5;

  const int colc = ((((l & 3) << 4) ^ (((l >> 2) & 8) << 2)) >> 1);
  const u16* Ag = A + (size_t)(bm * 256 + w * 16 + (l >> 2)) * K + colc;
  const u16* Bg = Bt + (size_t)(bn * 128 + w * 16 + (l >> 2)) * K + colc;
  const int ldst = w << 10;

  auto stage = [&](int t, char* buf) {
    const int kb = t << 5;
    gload16(Ag + kb, buf + ldst);
    gload16(Ag + (size_t)128 * K + kb, buf + 8192 + ldst);
    gload16(Bg + kb, buf + 16384 + ldst);
  };

  const int lo = ((l & 15) << 6) + (((l >> 4) << 4) ^ ((l & 8) << 2));

  f32x4 acc[4][4];
#pragma unroll
  for (int m = 0; m < 4; ++m)
#pragma unroll
    for (int n = 0; n < 4; ++n) acc[m][n] = f32x4{0.f, 0.f, 0.f, 0.f};

  char* p0 = lds;
  char* p1 = lds + SLAB;
  char* p2 = lds + 2 * SLAB;

  stage(0, p0);
  stage(1, p1);
  asm volatile("s_waitcnt vmcnt(3)" ::: "memory");
  __builtin_amdgcn_s_barrier();

  for (int t = 0; t < NT; ++t) {
    if (t + 2 < NT) stage(t + 2, p2);
    const char* ab = p0 + (wr << 12);
    const char* bb = p0 + 16384 + (wc << 12);
    bf16x8 af[4], bf[4];
#pragma unroll
    for (int m = 0; m < 4; ++m) af[m] = *(const bf16x8*)(ab + (m << 10) + lo);
#pragma unroll
    for (int n = 0; n < 4; ++n) bf[n] = *(const bf16x8*)(bb + (n << 10) + lo);
    __builtin_amdgcn_s_setprio(1);
#pragma unroll
    for (int m = 0; m < 4; ++m)
#pragma unroll
      for (int n = 0; n < 4; ++n)
        acc[m][n] = __builtin_amdgcn_mfma_f32_16x16x32_bf16(af[m], bf[n], acc[m][n], 0, 0, 0);
    __builtin_amdgcn_s_setprio(0);
    if (t + 2 < NT) asm volatile("s_waitcnt vmcnt(3)" ::: "memory");
    else            asm volatile("s_waitcnt vmcnt(0)" ::: "memory");
    __builtin_amdgcn_s_barrier();
    char* tmp = p0; p0 = p1; p1 = p2; p2 = tmp;
  }

  const int fr = l & 15, fq = l >> 4;
  const int colb = bn * 128 + wc * 64;
  const int rowb = bm * 256 + wr * 64;
  float bv[4];
#pragma unroll
  for (int n = 0; n < 4; ++n) bv[n] = bias[colb + n * 16 + fr];
  const int region = colb >> 10;

#pragma unroll
  for (int m = 0; m < 4; ++m) {
#pragma unroll
    for (int n = 0; n < 4; ++n) {
      const int col = colb + n * 16 + fr;
      if (MODE == 0 && region == 2) {
        const int row0_ = rowb + m * 16 + fq * 4;
        const int bI = row0_ >> 7, tl0 = row0_ & 127;
        const int c = col & 1023, h = c >> 6, d = c & 63;
        ushort4 pk;
        pk.x = f2bf(acc[m][n][0] + bv[n]);
        pk.y = f2bf(acc[m][n][1] + bv[n]);
        pk.z = f2bf(acc[m][n][2] + bv[n]);
        pk.w = f2bf(acc[m][n][3] + bv[n]);
        *(ushort4*)&O2[(((size_t)bI * 16 + h) * 64 + d) * 128 + tl0] = pk;
      } else {
#pragma unroll
        for (int j = 0; j < 4; ++j) {
          const int row = rowb + m * 16 + fq * 4 + j;
          float v = acc[m][n][j] + bv[n];
          if (MODE == 2) v = gelu_exact(v);
          if (MODE == 0) {
            const int bI = row >> 7, tl = row & 127;
            const int c = col & 1023, h = c >> 6, d = c & 63;
            if (region == 0) O0[(((size_t)bI * 16 + h) * 128 + tl) * 64 + d] = f2bf(v);
            else             O1[(((size_t)bI * 16 + h) * 128 + tl) * 64 + d] = f2bf(v);
          } else {
            O0[(size_t)row * N + col] = f2bf(v);
          }
        }
      }
    }
  }
}

// ------- small GEMM (N=1024): 256 thr, 4 waves, BM=BN=128, BK=32, 3 blocks/CU --------
// 3-buf depth-2 counted vmcnt; bf16 out + bias. grid = (M/128)*(N/128) = 512.
__launch_bounds__(256, 3)
__global__ void gemm4(const u16* __restrict__ A, const u16* __restrict__ Bt,
                      const float* __restrict__ bias, u16* __restrict__ O,
                      int N, int K) {
  extern __shared__ char lds[];
  constexpr int SLAB = 16384;  // A 128x32 (8KB) + B 128x32 (8KB)
  const int tid = threadIdx.x;
  const int w = tid >> 6, l = tid & 63;
  const int wr = w >> 1, wc = w & 1;
  const int nwg = gridDim.x;
  const int wg = (blockIdx.x & 7) * (nwg >> 3) + (blockIdx.x >> 3);
  const int ntn = N >> 7;
  const int bm = wg / ntn, bn = wg - (wg / ntn) * ntn;
  const int NT = K >> 5;

  const int colc = ((((l & 3) << 4) ^ (((l >> 2) & 8) << 2)) >> 1);
  const u16* Ag = A + (size_t)(bm * 128 + w * 16 + (l >> 2)) * K + colc;
  const u16* Bg = Bt + (size_t)(bn * 128 + w * 16 + (l >> 2)) * K + colc;
  const int ldst = w << 10;

  auto stage = [&](int t, char* buf) {
    const int kb = t << 5;
    gload16(Ag + kb, buf + ldst);
    gload16(Ag + (size_t)64 * K + kb, buf + 4096 + ldst);
    gload16(Bg + kb, buf + 8192 + ldst);
    gload16(Bg + (size_t)64 * K + kb, buf + 12288 + ldst);
  };

  const int lo = ((l & 15) << 6) + (((l >> 4) << 4) ^ ((l & 8) << 2));

  f32x4 acc[4][4];
#pragma unroll
  for (int m = 0; m < 4; ++m)
#pragma unroll
    for (int n = 0; n < 4; ++n) acc[m][n] = f32x4{0.f, 0.f, 0.f, 0.f};

  char* p0 = lds;
  char* p1 = lds + SLAB;
  char* p2 = lds + 2 * SLAB;

  stage(0, p0);
  stage(1, p1);
  asm volatile("s_waitcnt vmcnt(4)" ::: "memory");
  __builtin_amdgcn_s_barrier();

  for (int t = 0; t < NT; ++t) {
    if (t + 2 < NT) stage(t + 2, p2);
    const char* ab = p0 + (wr << 12);
    const char* bb = p0 + 8192 + (wc << 12);
    bf16x8 af[4], bf[4];
#pragma unroll
    for (int m = 0; m < 4; ++m) af[m] = *(const bf16x8*)(ab + (m << 10) + lo);
#pragma unroll
    for (int n = 0; n < 4; ++n) bf[n] = *(const bf16x8*)(bb + (n << 10) + lo);
    __builtin_amdgcn_s_setprio(1);
#pragma unroll
    for (int m = 0; m < 4; ++m)
#pragma unroll
      for (int n = 0; n < 4; ++n)
        acc[m][n] = __builtin_amdgcn_mfma_f32_16x16x32_bf16(af[m], bf[n], acc[m][n], 0, 0, 0);
    __builtin_amdgcn_s_setprio(0);
    if (t + 2 < NT) asm volatile("s_waitcnt vmcnt(4)" ::: "memory");
    else            asm volatile("s_waitcnt vmcnt(0)" ::: "memory");
    __builtin_amdgcn_s_barrier();
    char* tmp = p0; p0 = p1; p1 = p2; p2 = tmp;
  }

  const int fr = l & 15, fq = l >> 4;
  const int colb = bn * 128 + wc * 64;
  const int rowb = bm * 128 + wr * 64;
  float bv[4];
#pragma unroll
  for (int n = 0; n < 4; ++n) bv[n] = bias[colb + n * 16 + fr];
#pragma unroll
  for (int m = 0; m < 4; ++m)
#pragma unroll
    for (int n = 0; n < 4; ++n) {
      const int col = colb + n * 16 + fr;
#pragma unroll
      for (int j = 0; j < 4; ++j) {
        const int row = rowb + m * 16 + fq * 4 + j;
        O[(size_t)row * N + col] = f2bf(acc[m][n][j] + bv[n]);
      }
    }
}

// ---------------- fused attention: one block per (b,h), vectorized mask loads ----------
__launch_bounds__(256)
__global__ void attn_kernel(const u16* __restrict__ Qg, const u16* __restrict__ Kg,
                            const u16* __restrict__ Vg,
                            const u16* __restrict__ mask,
                            u16* __restrict__ Og) {
  __shared__ u16 QK[2 * 128 * 64];
  __shared__ u16 Vt[64 * 128];
  const int tid = threadIdx.x;
  const int wv = tid >> 6;
  const int l = tid & 63;
  const int bh = blockIdx.x;
  const int b = bh >> 4;

  const char* Qs = (const char*)(Qg + (size_t)bh * 8192);
  const char* Ks = (const char*)(Kg + (size_t)bh * 8192);
  const char* Vs = (const char*)(Vg + (size_t)bh * 8192);
  char* QKb = (char*)QK;
  char* Vtb = (char*)Vt;
#pragma unroll
  for (int it = 0; it < 4; ++it) {
    const int r = it * 32 + (tid >> 3);
    const int cb = (tid & 7) * 16;
    const int sw = cb ^ ((r & 7) << 4);
    *(uint4*)(QKb + r * 128 + sw) = *(const uint4*)(Qs + r * 128 + cb);
    *(uint4*)(QKb + 16384 + r * 128 + sw) = *(const uint4*)(Ks + r * 128 + cb);
  }
#pragma unroll
  for (int it = 0; it < 4; ++it) {
    const int r = it * 16 + (tid >> 4);
    const int cb = (tid & 15) * 16;
    const int sw = cb ^ ((r & 7) << 4);
    *(uint4*)(Vtb + r * 256 + sw) = *(const uint4*)(Vs + r * 256 + cb);
  }
  __syncthreads();

  f32x4 s[2][8];
#pragma unroll
  for (int m = 0; m < 2; ++m)
#pragma unroll
    for (int n = 0; n < 8; ++n) s[m][n] = f32x4{0.f, 0.f, 0.f, 0.f};
#pragma unroll
  for (int kk = 0; kk < 2; ++kk) {
    bf16x8 qa[2], kb[8];
#pragma unroll
    for (int m = 0; m < 2; ++m) {
      const int qr = wv * 32 + m * 16 + (l & 15);
      qa[m] = *(const bf16x8*)(QKb + qr * 128 + ((kk * 64 + (l >> 4) * 16) ^ ((qr & 7) << 4)));
    }
#pragma unroll
    for (int n = 0; n < 8; ++n) {
      const int kr = n * 16 + (l & 15);
      kb[n] = *(const bf16x8*)(QKb + 16384 + kr * 128 + ((kk * 64 + (l >> 4) * 16) ^ ((kr & 7) << 4)));
    }
#pragma unroll
    for (int m = 0; m < 2; ++m)
#pragma unroll
      for (int n = 0; n < 8; ++n)
        s[m][n] = __builtin_amdgcn_mfma_f32_16x16x32_bf16(qa[m], kb[n], s[m][n], 0, 0, 0);
  }

  // mask base for this thread's column slot (fr = l&15): [bh][fr][lq][n]
  const u16* mb2 = mask + (((size_t)bh * 16 + (l & 15)) << 10);
  float rinv[2][4];
#pragma unroll
  for (int m = 0; m < 2; ++m) {
#pragma unroll
    for (int j = 0; j < 4; ++j) {
      const int lq = wv * 32 + m * 16 + (l >> 4) * 4 + j;
      const short8 mv = *(const short8*)(mb2 + lq * 8);
      float vals[8];
#pragma unroll
      for (int n = 0; n < 8; ++n)
        vals[n] = fmaf(s[m][n][j], 0.125f, bf2f((u16)mv[n]));
      float mx = vals[0];
#pragma unroll
      for (int n = 1; n < 8; ++n) mx = fmaxf(mx, vals[n]);
#pragma unroll
      for (int o = 1; o < 16; o <<= 1) mx = fmaxf(mx, __shfl_xor(mx, o, 64));
      float sum = 0.f;
#pragma unroll
      for (int n = 0; n < 8; ++n) { vals[n] = expf(vals[n] - mx); sum += vals[n]; }
#pragma unroll
      for (int o = 1; o < 16; o <<= 1) sum += __shfl_xor(sum, o, 64);
      rinv[m][j] = 1.f / sum;
#pragma unroll
      for (int n = 0; n < 8; ++n) s[m][n][j] = vals[n];
    }
  }
  __syncthreads();
  char* Pb = QKb + wv * 8192;
#pragma unroll
  for (int m = 0; m < 2; ++m)
#pragma unroll
    for (int n = 0; n < 8; ++n)
#pragma unroll
      for (int j = 0; j < 4; ++j) {
        const int pr = m * 16 + (l >> 4) * 4 + j;
        const int pc = (n * 16 + (l & 15)) * 2;
        *(u16*)(Pb + pr * 256 + (pc ^ ((pr & 7) << 4))) = f2bf(s[m][n][j]);
      }
  __syncthreads();

  f32x4 o_[2][4];
#pragma unroll
  for (int m = 0; m < 2; ++m)
#pragma unroll
    for (int n = 0; n < 4; ++n) o_[m][n] = f32x4{0.f, 0.f, 0.f, 0.f};
#pragma unroll
  for (int ks = 0; ks < 4; ++ks) {
    bf16x8 pa[2], vb[4];
#pragma unroll
    for (int m = 0; m < 2; ++m) {
      const int pr = m * 16 + (l & 15);
      pa[m] = *(const bf16x8*)(Pb + pr * 256 + ((ks * 64 + (l >> 4) * 16) ^ ((pr & 7) << 4)));
    }
#pragma unroll
    for (int n = 0; n < 4; ++n) {
      const int vr = n * 16 + (l & 15);
      vb[n] = *(const bf16x8*)(Vtb + vr * 256 + ((ks * 64 + (l >> 4) * 16) ^ ((vr & 7) << 4)));
    }
#pragma unroll
    for (int m = 0; m < 2; ++m)
#pragma unroll
      for (int n = 0; n < 4; ++n)
        o_[m][n] = __builtin_amdgcn_mfma_f32_16x16x32_bf16(pa[m], vb[n], o_[m][n], 0, 0, 0);
  }
  const int h = bh & 15;
#pragma unroll
  for (int m = 0; m < 2; ++m)
#pragma unroll
    for (int n = 0; n < 4; ++n)
#pragma unroll
      for (int j = 0; j < 4; ++j) {
        const int lo2 = wv * 32 + m * 16 + (l >> 4) * 4 + j;
        const int d = n * 16 + (l & 15);
        Og[((size_t)b * 128 + lo2) * 1024 + h * 64 + d] = f2bf(o_[m][n][j] * rinv[m][j]);
      }
}

// ---------------- residual + LayerNorm, bf16 stream, vectorized ----------------
__launch_bounds__(256)
__global__ void ln_res(u16* __restrict__ xb, const u16* __restrict__ o,
                       const float* __restrict__ gam, const float* __restrict__ bet,
                       float* __restrict__ cls_out) {
  const int row = blockIdx.x * 4 + (threadIdx.x >> 6);
  const int l = threadIdx.x & 63;
  const size_t base = (size_t)row * 1024 + l * 16;
  const int c0 = l * 16;
  float v[16], gv[16], bb[16];
  const short8 xa = *(const short8*)(xb + base);
  const short8 xc = *(const short8*)(xb + base + 8);
  const short8 oa = *(const short8*)(o + base);
  const short8 oc = *(const short8*)(o + base + 8);
#pragma unroll
  for (int i = 0; i < 4; ++i) {
    *(float4*)&gv[i * 4] = *(const float4*)(gam + c0 + i * 4);
    *(float4*)&bb[i * 4] = *(const float4*)(bet + c0 + i * 4);
  }
  float s = 0.f, sq = 0.f;
#pragma unroll
  for (int i = 0; i < 8; ++i) {
    v[i] = bf2f((u16)xa[i]) + bf2f((u16)oa[i]);
    v[i + 8] = bf2f((u16)xc[i]) + bf2f((u16)oc[i]);
  }
#pragma unroll
  for (int i = 0; i < 16; ++i) { s += v[i]; sq += v[i] * v[i]; }
#pragma unroll
  for (int off = 1; off < 64; off <<= 1) {
    s += __shfl_xor(s, off, 64);
    sq += __shfl_xor(sq, off, 64);
  }
  const float mean = s * (1.f / 1024.f);
  const float var = sq * (1.f / 1024.f) - mean * mean;
  const float rstd = rsqrtf(var + 1e-5f);
  short8 ra, rc;
#pragma unroll
  for (int i = 0; i < 8; ++i) {
    const float ya = (v[i] - mean) * rstd * gv[i] + bb[i];
    const float yc = (v[i + 8] - mean) * rstd * gv[i + 8] + bb[i + 8];
    ra[i] = (short)f2bf(ya);
    rc[i] = (short)f2bf(yc);
    if ((row & 127) == 0) {
      cls_out[(size_t)(row >> 7) * 1024 + c0 + i] = ya;
      cls_out[(size_t)(row >> 7) * 1024 + c0 + 8 + i] = yc;
    }
  }
  *(short8*)(xb + base) = ra;
  *(short8*)(xb + base + 8) = rc;
}

extern "C" void kernel_launch(void* const* d_in, const int* in_sizes, int n_in,
                              void* d_out, int out_size, void* d_ws, size_t ws_size,
                              hipStream_t stream) {
  const int* z = (const int*)d_in[0];
  const int* hgs = (const int*)d_in[1];
  const float* pos = (const float*)d_in[2];
  const float* atoms_emb = (const float*)d_in[4];
  const float* neigh_emb = (const float*)d_in[5];
  const float* dist_emb = (const float*)d_in[6];
  const float* Wqkv = (const float*)d_in[7];
  const float* bqkv = (const float*)d_in[8];
  const float* Wo = (const float*)d_in[9];
  const float* bo = (const float*)d_in[10];
  const float* W1 = (const float*)d_in[11];
  const float* b1f = (const float*)d_in[12];
  const float* W2 = (const float*)d_in[13];
  const float* b2f = (const float*)d_in[14];
  const float* ln1g = (const float*)d_in[15];
  const float* ln1b = (const float*)d_in[16];
  const float* ln2g = (const float*)d_in[17];
  const float* ln2b = (const float*)d_in[18];

  size_t off = 0;
  char* wsb = (char*)d_ws;
  auto alc = [&](size_t bytes) { void* p = wsb + off; off += (bytes + 255) & ~(size_t)255; return p; };
  u16* xb = (u16*)alc(8192ull * 1024 * 2);
  u16* q = (u16*)alc(8192ull * 1024 * 2);
  u16* k = (u16*)alc(8192ull * 1024 * 2);
  u16* v = (u16*)alc(8192ull * 1024 * 2);
  u16* proj = (u16*)alc(8192ull * 1024 * 2);
  u16* big = (u16*)alc(8192ull * 3072 * 2);
  u16* wqkvt = (u16*)alc(3072ull * 1024 * 2);
  u16* wot = (u16*)alc(1024ull * 1024 * 2);
  u16* w1t = (u16*)alc(3072ull * 1024 * 2);
  u16* w2t = (u16*)alc(1024ull * 3072 * 2);
  u16* mask = (u16*)alc(64ull * 16 * 16 * 128 * 8 * 2);

  hipFuncSetAttribute((const void*)gemmS<0>, hipFuncAttributeMaxDynamicSharedMemorySize, 73728);
  hipFuncSetAttribute((const void*)gemmS<2>, hipFuncAttributeMaxDynamicSharedMemorySize, 73728);
  hipFuncSetAttribute((const void*)gemm4, hipFuncAttributeMaxDynamicSharedMemorySize, 49152);

  transpose_w<<<dim3(96, 32), dim3(32, 8), 0, stream>>>(Wqkv, wqkvt, 1024, 3072);
  transpose_w<<<dim3(32, 32), dim3(32, 8), 0, stream>>>(Wo, wot, 1024, 1024);
  transpose_w<<<dim3(96, 32), dim3(32, 8), 0, stream>>>(W1, w1t, 1024, 3072);
  transpose_w<<<dim3(32, 96), dim3(32, 8), 0, stream>>>(W2, w2t, 3072, 1024);
  embed_k<<<8192, 256, 0, stream>>>(z, hgs, atoms_emb, neigh_emb, xb);
  mask_k<<<8192, 128, 0, stream>>>(pos, dist_emb, mask);

  float* cls = (float*)d_out;
  for (int layer = 0; layer < 8; ++layer) {
    gemmS<0><<<768, 512, 73728, stream>>>(xb, wqkvt, bqkv, q, k, v, 3072, 1024);
    attn_kernel<<<1024, 256, 0, stream>>>(q, k, v, mask, big);
    gemm4<<<512, 256, 49152, stream>>>(big, wot, bo, proj, 1024, 1024);
    ln_res<<<2048, 256, 0, stream>>>(xb, proj, ln1g, ln1b, cls);
    gemmS<2><<<768, 512, 73728, stream>>>(xb, w1t, b1f, big, nullptr, nullptr, 3072, 1024);
    gemm4<<<512, 256, 49152, stream>>>(big, w2t, b2f, proj, 1024, 3072);
    ln_res<<<2048, 256, 0, stream>>>(xb, proj, ln2g, ln2b, cls);
  }
}